// Round 2
// baseline (808.026 us; speedup 1.0000x reference)
//
#include <hip/hip_runtime.h>
#include <hip/hip_bf16.h>
#include <cstdio>

#define LQ 2048      // L
#define BB 2         // batch
#define BL 4096      // B*L rows
#define DMODEL 2048
#define DIN 4096
#define NH 64
#define HD 64
#define NST 128
#define CONVD 4352
#define PROJD 8512
#define PROJ_PAD 8576
#define PXW 4416     // projx width: CONVD + NH
#define CHK 256
#define NCH 8        // chunks per batch

typedef __attribute__((ext_vector_type(8))) short short8;
typedef __attribute__((ext_vector_type(4))) float f32x4;
typedef __attribute__((ext_vector_type(4))) unsigned int u32x4;

__device__ __forceinline__ unsigned short f2bu(float x) {
  __hip_bfloat16 h = __float2bfloat16(x);
  return __builtin_bit_cast(unsigned short, h);
}

__device__ __forceinline__ f32x4 mfma16(short8 a, short8 b, f32x4 c) {
  return __builtin_amdgcn_mfma_f32_16x16x32_bf16(a, b, c, 0, 0, 0);
}

// ---------------- cast fp32 -> bf16 (with zero tail padding) ----------------
__global__ void k_cast_pad(const float* __restrict__ in, unsigned short* __restrict__ out,
                           long n, long ntot) {
  long i = (long)blockIdx.x * blockDim.x + threadIdx.x;
  long stride = (long)gridDim.x * blockDim.x;
  for (; i < ntot; i += stride)
    out[i] = (i < n) ? f2bu(in[i]) : (unsigned short)0;
}

// ---- bf16 GEMM: C(M,Nreal) = A(M,K) @ B(Npad,K)^T -------------------------
// SPLIT=true: cols [0,DIN) -> bf16 gateb; cols [DIN,PROJD) -> fp32 projx.
template <bool SPLIT>
__global__ __launch_bounds__(256) void k_gemm_bt(
    const unsigned short* __restrict__ A, const unsigned short* __restrict__ Bw,
    float* __restrict__ C, unsigned short* __restrict__ gateb,
    float* __restrict__ projx, int Nreal, int K) {
  __shared__ unsigned short lA[128][72];
  __shared__ unsigned short lB[128][72];
  const int tid = threadIdx.x;
  const int lane = tid & 63, w = tid >> 6;
  const int m0 = blockIdx.y * 128, n0 = blockIdx.x * 128;
  const int wr = (w >> 1) * 64, wc = (w & 1) * 64;
  f32x4 acc[4][4] = {};
  for (int kb = 0; kb < K; kb += 64) {
#pragma unroll
    for (int i = 0; i < 4; i++) {
      int cidx = tid + 256 * i;
      int r = cidx >> 3, cc = cidx & 7;
      *reinterpret_cast<u32x4*>(&lA[r][cc * 8]) =
          *reinterpret_cast<const u32x4*>(A + (size_t)(m0 + r) * K + kb + cc * 8);
      *reinterpret_cast<u32x4*>(&lB[r][cc * 8]) =
          *reinterpret_cast<const u32x4*>(Bw + (size_t)(n0 + r) * K + kb + cc * 8);
    }
    __syncthreads();
#pragma unroll
    for (int kk = 0; kk < 64; kk += 32) {
      short8 af[4], bf[4];
      const int ko = kk + ((lane >> 4) << 3);
#pragma unroll
      for (int i = 0; i < 4; i++) {
        af[i] = *reinterpret_cast<const short8*>(&lA[wr + i * 16 + (lane & 15)][ko]);
        bf[i] = *reinterpret_cast<const short8*>(&lB[wc + i * 16 + (lane & 15)][ko]);
      }
#pragma unroll
      for (int mi = 0; mi < 4; mi++)
#pragma unroll
        for (int ni = 0; ni < 4; ni++)
          acc[mi][ni] = mfma16(af[mi], bf[ni], acc[mi][ni]);
    }
    __syncthreads();
  }
#pragma unroll
  for (int mi = 0; mi < 4; mi++) {
    const int row = m0 + wr + mi * 16 + ((lane >> 4) << 2);
#pragma unroll
    for (int ni = 0; ni < 4; ni++) {
      const int col = n0 + wc + ni * 16 + (lane & 15);
      if (SPLIT) {
        if (col < DIN) {
#pragma unroll
          for (int v = 0; v < 4; v++)
            gateb[(size_t)(row + v) * DIN + col] = f2bu(acc[mi][ni][v]);
        } else if (col < PROJD) {
#pragma unroll
          for (int v = 0; v < 4; v++)
            projx[(size_t)(row + v) * PXW + (col - DIN)] = acc[mi][ni][v];
        }
      } else {
        if (col < Nreal) {
#pragma unroll
          for (int v = 0; v < 4; v++)
            C[(size_t)(row + v) * Nreal + col] = acc[mi][ni][v];
        }
      }
    }
  }
}

// ---------------- causal depthwise conv (K=4) + SiLU ------------------------
__global__ __launch_bounds__(256) void k_conv_silu(
    const float* __restrict__ projx, const float* __restrict__ cw,
    const float* __restrict__ cb, float* __restrict__ xbc) {
  const int ch = blockIdx.x * 256 + threadIdx.x;  // 17*256 = 4352 exact
  const int bt = blockIdx.y;
  const int b = bt >> 11, t = bt & 2047;
  float acc = cb[ch];
#pragma unroll
  for (int i = 0; i < 4; i++) {
    int tt = t - 3 + i;
    if (tt >= 0)
      acc += cw[ch * 4 + i] * projx[((size_t)b * LQ + tt) * PXW + ch];
  }
  float o = acc / (1.f + __expf(-acc));
  xbc[(size_t)bt * CONVD + ch] = o;
}

// ---------------- dt softplus + per-chunk cumsum(dt*A) ----------------------
__global__ void k_dt(const float* __restrict__ projx, const float* __restrict__ dtb,
                     const float* __restrict__ alog, float* __restrict__ dtv,
                     float* __restrict__ dac) {
  const int bc = blockIdx.x;  // 16 = b*8+c
  const int b = bc >> 3, c = bc & 7;
  const int h = threadIdx.x;  // 64
  const float bias = dtb[h];
  const float Ah = -__expf(alog[h]);
  float cum = 0.f;
  for (int s = 0; s < CHK; s++) {
    size_t row = (size_t)b * LQ + c * CHK + s;
    float raw = projx[row * PXW + CONVD + h] + bias;
    float dt = raw > 20.f ? raw : log1pf(__expf(raw));
    dtv[row * NH + h] = dt;
    cum += dt * Ah;
    dac[row * NH + h] = cum;
  }
}

// ---------------- CB[t][s] = sum_n C[t][n]*B[s][n] per (b,c) ----------------
__global__ __launch_bounds__(256) void k_cb(const float* __restrict__ xbc,
                                            float* __restrict__ cbuf) {
  const int q = blockIdx.x;   // 4 quadrants
  const int bc = blockIdx.y;  // 16
  const int b = bc >> 3, c = bc & 7;
  const int qt = q >> 1, qs = q & 1;
  __shared__ unsigned short lC[128][136];
  __shared__ unsigned short lB[128][136];
  const int tid = threadIdx.x, lane = tid & 63, w = tid >> 6;
  {
    int r = tid >> 1, hf = tid & 1;
    size_t rowc = (size_t)b * LQ + c * CHK + qt * 128 + r;
    const float* crp = xbc + rowc * CONVD + DIN + NST + hf * 64;
    size_t rowb = (size_t)b * LQ + c * CHK + qs * 128 + r;
    const float* brp = xbc + rowb * CONVD + DIN + hf * 64;
#pragma unroll
    for (int n = 0; n < 64; n++) {
      lC[r][hf * 64 + n] = f2bu(crp[n]);
      lB[r][hf * 64 + n] = f2bu(brp[n]);
    }
  }
  __syncthreads();
  const int wr = (w >> 1) * 64, wc = (w & 1) * 64;
  f32x4 acc[4][4] = {};
#pragma unroll
  for (int kk = 0; kk < 128; kk += 32) {
    short8 a[4], bb[4];
    const int ko = kk + ((lane >> 4) << 3);
#pragma unroll
    for (int i = 0; i < 4; i++) {
      a[i] = *reinterpret_cast<const short8*>(&lC[wr + i * 16 + (lane & 15)][ko]);
      bb[i] = *reinterpret_cast<const short8*>(&lB[wc + i * 16 + (lane & 15)][ko]);
    }
#pragma unroll
    for (int mi = 0; mi < 4; mi++)
#pragma unroll
      for (int ni = 0; ni < 4; ni++)
        acc[mi][ni] = mfma16(a[mi], bb[ni], acc[mi][ni]);
  }
  float* outp = cbuf + (size_t)bc * (CHK * CHK);
#pragma unroll
  for (int mi = 0; mi < 4; mi++) {
    const int t = qt * 128 + wr + mi * 16 + ((lane >> 4) << 2);
#pragma unroll
    for (int ni = 0; ni < 4; ni++) {
      const int s = qs * 128 + wc + ni * 16 + (lane & 15);
#pragma unroll
      for (int v = 0; v < 4; v++)
        outp[(size_t)(t + v) * CHK + s] = acc[mi][ni][v];
    }
  }
}

// ---------------- fused Y_diag + states per (b,c,h) -------------------------
__global__ __launch_bounds__(256) void k_diag(
    const float* __restrict__ xbc, const float* __restrict__ dtv,
    const float* __restrict__ dac, const float* __restrict__ cbuf,
    float* __restrict__ y, float* __restrict__ st) {
  const int h = blockIdx.x, c = blockIdx.y, b = blockIdx.z;
  const int cs = c * CHK;
  __shared__ unsigned short lXt[64][264];   // (p, s) x*dt, bf16
  __shared__ unsigned short lBt[128][264];  // (n, s) B*decay, bf16
  __shared__ unsigned short lS[256][40];    // (t, s-block32) masked S, bf16
  __shared__ float lda[256];
  const int tid = threadIdx.x, lane = tid & 63, w = tid >> 6;
  lda[tid] = dac[((size_t)b * LQ + cs + tid) * NH + h];
  __syncthreads();
  const float dalast = lda[255];
  {
    const int s = tid;
    const float* xrow = xbc + ((size_t)b * LQ + cs + s) * CONVD;
    const float dts = dtv[((size_t)b * LQ + cs + s) * NH + h];
    const f32x4* x4 = reinterpret_cast<const f32x4*>(xrow + h * HD);
#pragma unroll
    for (int p4 = 0; p4 < 16; p4++) {
      f32x4 v = x4[p4];
#pragma unroll
      for (int u = 0; u < 4; u++) lXt[p4 * 4 + u][s] = f2bu(v[u] * dts);
    }
    const float dec = __expf(dalast - lda[s]);
    const f32x4* b4 = reinterpret_cast<const f32x4*>(xrow + DIN);
#pragma unroll
    for (int n4 = 0; n4 < 32; n4++) {
      f32x4 v = b4[n4];
#pragma unroll
      for (int u = 0; u < 4; u++) lBt[n4 * 4 + u][s] = f2bu(v[u] * dec);
    }
  }
  __syncthreads();
  const float* cbp = cbuf + ((size_t)(b * NCH + c)) * (CHK * CHK);
  const float da_t = lda[tid];
  f32x4 accY[4][4] = {};
  f32x4 accS[4][2] = {};
  const int wn = w * 32;
  for (int sb = 0; sb < 8; sb++) {
    {
      const int t = tid;
      const f32x4* cr = reinterpret_cast<const f32x4*>(cbp + (size_t)t * CHK + sb * 32);
#pragma unroll
      for (int j4 = 0; j4 < 8; j4++) {
        f32x4 v = cr[j4];
#pragma unroll
        for (int u = 0; u < 4; u++) {
          int s = sb * 32 + j4 * 4 + u;
          float val = (s <= t) ? v[u] * __expf(da_t - lda[s]) : 0.f;
          lS[t][j4 * 4 + u] = f2bu(val);
        }
      }
    }
    __syncthreads();
    short8 sf[4], xf[4], btf[2];
    const int ko = ((lane >> 4) << 3);
#pragma unroll
    for (int i = 0; i < 4; i++) {
      sf[i] = *reinterpret_cast<const short8*>(&lS[w * 64 + i * 16 + (lane & 15)][ko]);
      xf[i] = *reinterpret_cast<const short8*>(&lXt[i * 16 + (lane & 15)][sb * 32 + ko]);
    }
#pragma unroll
    for (int i = 0; i < 2; i++)
      btf[i] = *reinterpret_cast<const short8*>(&lBt[wn + i * 16 + (lane & 15)][sb * 32 + ko]);
#pragma unroll
    for (int mi = 0; mi < 4; mi++)
#pragma unroll
      for (int ni = 0; ni < 4; ni++)
        accY[mi][ni] = mfma16(sf[mi], xf[ni], accY[mi][ni]);
#pragma unroll
    for (int mi = 0; mi < 4; mi++)
#pragma unroll
      for (int nj = 0; nj < 2; nj++)
        accS[mi][nj] = mfma16(xf[mi], btf[nj], accS[mi][nj]);
    __syncthreads();
  }
#pragma unroll
  for (int mi = 0; mi < 4; mi++) {
    const int t = w * 64 + mi * 16 + ((lane >> 4) << 2);
#pragma unroll
    for (int ni = 0; ni < 4; ni++) {
      const int p = ni * 16 + (lane & 15);
#pragma unroll
      for (int v = 0; v < 4; v++)
        y[((size_t)b * LQ + cs + t + v) * DIN + h * HD + p] = accY[mi][ni][v];
    }
  }
  float* stp = st + ((size_t)((b * NCH + c) * NH + h)) * (HD * NST);
#pragma unroll
  for (int mi = 0; mi < 4; mi++) {
    const int p = mi * 16 + ((lane >> 4) << 2);
#pragma unroll
    for (int nj = 0; nj < 2; nj++) {
      const int n = wn + nj * 16 + (lane & 15);
#pragma unroll
      for (int v = 0; v < 4; v++)
        stp[(size_t)(p + v) * NST + n] = accS[mi][nj][v];
    }
  }
}

// ---------------- inter-chunk state scan ------------------------------------
__global__ void k_scan(const float* __restrict__ st, const float* __restrict__ dac,
                       float* __restrict__ pv) {
  const int h = blockIdx.x, b = blockIdx.y;
  const int tid = threadIdx.x;
  float P[32];
#pragma unroll
  for (int j = 0; j < 32; j++) P[j] = 0.f;
  for (int c = 0; c < NCH; c++) {
    const size_t base = ((size_t)((b * NCH + c) * NH + h)) * (HD * NST);
#pragma unroll
    for (int j = 0; j < 32; j++) pv[base + tid + 256 * j] = P[j];
    const float d = __expf(dac[((size_t)b * LQ + c * CHK + 255) * NH + h]);
#pragma unroll
    for (int j = 0; j < 32; j++) P[j] = P[j] * d + st[base + tid + 256 * j];
  }
}

// ---------------- Y_off + D*x accumulate into y -----------------------------
__global__ __launch_bounds__(256) void k_off(
    const float* __restrict__ xbc, const float* __restrict__ dac,
    const float* __restrict__ pv, const float* __restrict__ Dp,
    float* __restrict__ y) {
  const int h = blockIdx.x, c = blockIdx.y, b = blockIdx.z;
  const int cs = c * CHK;
  __shared__ unsigned short lC[256][136];  // (t, n)
  __shared__ unsigned short lP[64][136];   // (p, n)
  __shared__ float lda[256];
  const int tid = threadIdx.x, lane = tid & 63, w = tid >> 6;
  {
    const int s = tid;
    lda[s] = dac[((size_t)b * LQ + cs + s) * NH + h];
    const f32x4* cr = reinterpret_cast<const f32x4*>(
        xbc + ((size_t)b * LQ + cs + s) * CONVD + DIN + NST);
#pragma unroll
    for (int n4 = 0; n4 < 32; n4++) {
      f32x4 v = cr[n4];
#pragma unroll
      for (int u = 0; u < 4; u++) lC[s][n4 * 4 + u] = f2bu(v[u]);
    }
  }
  if (tid < 64) {
    const f32x4* pr = reinterpret_cast<const f32x4*>(
        pv + ((size_t)((b * NCH + c) * NH + h)) * (HD * NST) + (size_t)tid * NST);
#pragma unroll
    for (int n4 = 0; n4 < 32; n4++) {
      f32x4 v = pr[n4];
#pragma unroll
      for (int u = 0; u < 4; u++) lP[tid][n4 * 4 + u] = f2bu(v[u]);
    }
  }
  __syncthreads();
  f32x4 acc[4][4] = {};
#pragma unroll
  for (int kk = 0; kk < 128; kk += 32) {
    short8 a[4], bb[4];
    const int ko = kk + ((lane >> 4) << 3);
#pragma unroll
    for (int i = 0; i < 4; i++) {
      a[i] = *reinterpret_cast<const short8*>(&lC[w * 64 + i * 16 + (lane & 15)][ko]);
      bb[i] = *reinterpret_cast<const short8*>(&lP[i * 16 + (lane & 15)][ko]);
    }
#pragma unroll
    for (int mi = 0; mi < 4; mi++)
#pragma unroll
      for (int ni = 0; ni < 4; ni++)
        acc[mi][ni] = mfma16(a[mi], bb[ni], acc[mi][ni]);
  }
  const float Dh = Dp[h];
#pragma unroll
  for (int mi = 0; mi < 4; mi++) {
    const int t = w * 64 + mi * 16 + ((lane >> 4) << 2);
#pragma unroll
    for (int ni = 0; ni < 4; ni++) {
      const int p = ni * 16 + (lane & 15);
#pragma unroll
      for (int v = 0; v < 4; v++) {
        const int tt = t + v;
        const size_t row = (size_t)b * LQ + cs + tt;
        const float scale = __expf(lda[tt]);
        const float xval = xbc[row * CONVD + h * HD + p];
        const size_t yi = row * DIN + h * HD + p;
        y[yi] += scale * acc[mi][ni][v] + Dh * xval;
      }
    }
  }
}

// ---------------- gate*silu + RMSNorm -> bf16 -------------------------------
__global__ __launch_bounds__(256) void k_gatenorm(
    const float* __restrict__ y, const unsigned short* __restrict__ gateb,
    const float* __restrict__ nw, unsigned short* __restrict__ hgb) {
  const int r = blockIdx.x;
  const int tid = threadIdx.x;
  const float* yr = y + (size_t)r * DIN;
  const unsigned short* gr = gateb + (size_t)r * DIN;
  float hg[16];
  float ss = 0.f;
#pragma unroll
  for (int j = 0; j < 16; j++) {
    const int d = tid + 256 * j;
    const float g = __bfloat162float(__builtin_bit_cast(__hip_bfloat16, gr[d]));
    const float v = yr[d] * (g / (1.f + __expf(-g)));
    hg[j] = v;
    ss += v * v;
  }
#pragma unroll
  for (int o = 32; o > 0; o >>= 1) ss += __shfl_down(ss, o);
  __shared__ float red[4];
  if ((tid & 63) == 0) red[tid >> 6] = ss;
  __syncthreads();
  const float tot = red[0] + red[1] + red[2] + red[3];
  const float scale = rsqrtf(tot / (float)DIN + 1e-5f);
#pragma unroll
  for (int j = 0; j < 16; j++) {
    const int d = tid + 256 * j;
    hgb[(size_t)r * DIN + d] = f2bu(hg[j] * scale * nw[d]);
  }
}

extern "C" void kernel_launch(void* const* d_in, const int* in_sizes, int n_in,
                              void* d_out, int out_size, void* d_ws, size_t ws_size,
                              hipStream_t stream) {
  const float* hidden = (const float*)d_in[0];
  const float* w1 = (const float*)d_in[1];
  const float* cw = (const float*)d_in[2];
  const float* cb = (const float*)d_in[3];
  const float* dtb = (const float*)d_in[4];
  const float* alog = (const float*)d_in[5];
  const float* Dp = (const float*)d_in[6];
  const float* nw = (const float*)d_in[7];
  const float* w2 = (const float*)d_in[8];
  float* out = (float*)d_out;
  char* ws = (char*)d_ws;

  // Lifetime-aliased layout (stages S1 casts+GEMM1 / S2 conv+dt / S3 ssd / S4
  // gatenorm / S5 GEMM2). Peak live = 245.4 MB < ws.
  const size_t OFF_GATEB = 0;            // bf16 4096x4096   S1-S4
  const size_t OFF_XBC = 33554432;       // f32 4096x4352    S2-S3
  const size_t OFF_DTV = 104857600;      // f32 4096x64      S2-S3
  const size_t OFF_DAC = 105906176;      // f32 4096x64      S2-S3
  const size_t OFF_CB = 106954752;       // f32 16x256x256   S3
  const size_t OFF_Y = 111149056;        // f32 4096x4096    S3-S4
  const size_t OFF_ST = 178257920;       // f32 1024x64x128  S3
  const size_t OFF_PV = 211812352;       // f32 1024x64x128  S3
  const size_t OFF_PROJX = 111149056;    // f32 4096x4416    S1-S2 (aliases Y+ST head)
  const size_t OFF_HB = 183500800;       // bf16 4096x2048   S1 (aliases ST tail+)
  const size_t OFF_W1B = 200278016;      // bf16 8576x2048   S1 (aliases PV)
  const size_t OFF_W2B = 0;              // bf16 2048x4096   S5 (aliases GATEB)
  const size_t OFF_HGB = 33554432;       // bf16 4096x4096   S4-S5 (aliases XBC)
  const size_t NEED = 245366784;
  if (ws_size < NEED) {
    fprintf(stderr, "WS TOO SMALL: %zu < %zu\n", ws_size, NEED);
    return;
  }
  unsigned short* gateb = (unsigned short*)(ws + OFF_GATEB);
  float* xbc = (float*)(ws + OFF_XBC);
  float* dtv = (float*)(ws + OFF_DTV);
  float* dac = (float*)(ws + OFF_DAC);
  float* cbuf = (float*)(ws + OFF_CB);
  float* y = (float*)(ws + OFF_Y);
  float* st = (float*)(ws + OFF_ST);
  float* pv = (float*)(ws + OFF_PV);
  float* projx = (float*)(ws + OFF_PROJX);
  unsigned short* hb = (unsigned short*)(ws + OFF_HB);
  unsigned short* w1b = (unsigned short*)(ws + OFF_W1B);
  unsigned short* w2b = (unsigned short*)(ws + OFF_W2B);
  unsigned short* hgb = (unsigned short*)(ws + OFF_HGB);

  // S1
  k_cast_pad<<<4096, 256, 0, stream>>>(hidden, hb, (long)BL * DMODEL, (long)BL * DMODEL);
  k_cast_pad<<<8192, 256, 0, stream>>>(w1, w1b, (long)PROJD * DMODEL, (long)PROJ_PAD * DMODEL);
  k_gemm_bt<true><<<dim3(PROJ_PAD / 128, BL / 128), 256, 0, stream>>>(
      hb, w1b, nullptr, gateb, projx, PROJD, DMODEL);
  // S2
  k_conv_silu<<<dim3(17, BL), 256, 0, stream>>>(projx, cw, cb, xbc);
  k_dt<<<16, 64, 0, stream>>>(projx, dtb, alog, dtv, dac);
  // S3
  k_cb<<<dim3(4, 16), 256, 0, stream>>>(xbc, cbuf);
  k_diag<<<dim3(NH, NCH, BB), 256, 0, stream>>>(xbc, dtv, dac, cbuf, y, st);
  k_scan<<<dim3(NH, BB), 256, 0, stream>>>(st, dac, pv);
  k_off<<<dim3(NH, NCH, BB), 256, 0, stream>>>(xbc, dac, pv, Dp, y);
  // S4
  k_gatenorm<<<BL, 256, 0, stream>>>(y, gateb, nw, hgb);
  // S5
  k_cast_pad<<<8192, 256, 0, stream>>>(w2, w2b, (long)DMODEL * DIN, (long)DMODEL * DIN);
  k_gemm_bt<false><<<dim3(DMODEL / 128, BL / 128), 256, 0, stream>>>(
      hgb, w2b, out, nullptr, nullptr, DMODEL, DIN);
}

// Round 3
// 743.922 us; speedup vs baseline: 1.0862x; 1.0862x over previous
//
#include <hip/hip_runtime.h>
#include <hip/hip_bf16.h>
#include <cstdio>

#define LQ 2048      // L
#define BB 2         // batch
#define BL 4096      // B*L rows
#define DMODEL 2048
#define DIN 4096
#define NH 64
#define HD 64
#define NST 128
#define CONVD 4352
#define PROJD 8512
#define PROJ_PAD 8576
#define PXW 4416     // projx width: CONVD + NH
#define CHK 256
#define NCH 8        // chunks per batch

typedef __attribute__((ext_vector_type(8))) short short8;
typedef __attribute__((ext_vector_type(4))) float f32x4;
typedef __attribute__((ext_vector_type(4))) unsigned int u32x4;

__device__ __forceinline__ unsigned short f2bu(float x) {
  __hip_bfloat16 h = __float2bfloat16(x);
  return __builtin_bit_cast(unsigned short, h);
}

__device__ __forceinline__ f32x4 mfma16(short8 a, short8 b, f32x4 c) {
  return __builtin_amdgcn_mfma_f32_16x16x32_bf16(a, b, c, 0, 0, 0);
}

#define GLD16(gptr, lptr)                                                  \
  __builtin_amdgcn_global_load_lds(                                        \
      (const __attribute__((address_space(1))) void*)(gptr),               \
      (__attribute__((address_space(3))) void*)(lptr), 16, 0, 0)

// ---------------- cast fp32 -> bf16 (with zero tail padding) ----------------
__global__ void k_cast_pad(const float* __restrict__ in, unsigned short* __restrict__ out,
                           long n, long ntot) {
  long i = (long)blockIdx.x * blockDim.x + threadIdx.x;
  long stride = (long)gridDim.x * blockDim.x;
  for (; i < ntot; i += stride)
    out[i] = (i < n) ? f2bu(in[i]) : (unsigned short)0;
}

// ---- bf16 GEMM: C(M,Nreal) = A(M,K) @ B(Npad,K)^T -------------------------
// m97 structure: global_load_lds width=16, linear LDS, XCD-swizzled blocks.
// SPLIT=true: cols [0,DIN) -> bf16 gateb; cols [DIN,PROJD) -> fp32 projx.
template <bool SPLIT>
__global__ __launch_bounds__(256) void k_gemm_bt(
    const unsigned short* __restrict__ A, const unsigned short* __restrict__ Bw,
    float* __restrict__ C, unsigned short* __restrict__ gateb,
    float* __restrict__ projx, int Nreal, int K) {
  __shared__ unsigned short lA[128][64];
  __shared__ unsigned short lB[128][64];
  const int tid = threadIdx.x;
  const int lane = tid & 63, w = tid >> 6;
  // XCD-aware bijective swizzle (nwg % 8 == 0 for both call sites)
  const int gx = gridDim.x;
  const int nwg = gx * gridDim.y;
  const int bid = blockIdx.y * gx + blockIdx.x;
  const int qq = nwg >> 3;
  const int swz = (bid & 7) * qq + (bid >> 3);
  const int m0 = (swz / gx) * 128, n0 = (swz % gx) * 128;
  const int wr = (w >> 1) * 64, wc = (w & 1) * 64;
  // staging coords: thread -> (row, col8) within 128x64 tile
  const int sr = tid >> 3, sc = (tid & 7) * 8;
  f32x4 acc[4][4] = {};
  for (int kb = 0; kb < K; kb += 64) {
#pragma unroll
    for (int i = 0; i < 4; i++) {
      const int r = sr + i * 32;
      GLD16(A + (size_t)(m0 + r) * K + kb + sc, &lA[r][sc]);
      GLD16(Bw + (size_t)(n0 + r) * K + kb + sc, &lB[r][sc]);
    }
    __syncthreads();
#pragma unroll
    for (int kk = 0; kk < 64; kk += 32) {
      short8 af[4], bf[4];
      const int ko = kk + ((lane >> 4) << 3);
#pragma unroll
      for (int i = 0; i < 4; i++) {
        af[i] = *reinterpret_cast<const short8*>(&lA[wr + i * 16 + (lane & 15)][ko]);
        bf[i] = *reinterpret_cast<const short8*>(&lB[wc + i * 16 + (lane & 15)][ko]);
      }
#pragma unroll
      for (int mi = 0; mi < 4; mi++)
#pragma unroll
        for (int ni = 0; ni < 4; ni++)
          acc[mi][ni] = mfma16(af[mi], bf[ni], acc[mi][ni]);
    }
    __syncthreads();
  }
#pragma unroll
  for (int mi = 0; mi < 4; mi++) {
    const int row = m0 + wr + mi * 16 + ((lane >> 4) << 2);
#pragma unroll
    for (int ni = 0; ni < 4; ni++) {
      const int col = n0 + wc + ni * 16 + (lane & 15);
      if (SPLIT) {
        if (col < DIN) {
#pragma unroll
          for (int v = 0; v < 4; v++)
            gateb[(size_t)(row + v) * DIN + col] = f2bu(acc[mi][ni][v]);
        } else if (col < PROJD) {
#pragma unroll
          for (int v = 0; v < 4; v++)
            projx[(size_t)(row + v) * PXW + (col - DIN)] = acc[mi][ni][v];
        }
      } else {
        if (col < Nreal) {
#pragma unroll
          for (int v = 0; v < 4; v++)
            C[(size_t)(row + v) * Nreal + col] = acc[mi][ni][v];
        }
      }
    }
  }
}

// ---------------- causal depthwise conv (K=4) + SiLU ------------------------
__global__ __launch_bounds__(256) void k_conv_silu(
    const float* __restrict__ projx, const float* __restrict__ cw,
    const float* __restrict__ cb, float* __restrict__ xbc) {
  const int ch = blockIdx.x * 256 + threadIdx.x;  // 17*256 = 4352 exact
  const int bt = blockIdx.y;
  const int b = bt >> 11, t = bt & 2047;
  float acc = cb[ch];
#pragma unroll
  for (int i = 0; i < 4; i++) {
    int tt = t - 3 + i;
    if (tt >= 0)
      acc += cw[ch * 4 + i] * projx[((size_t)b * LQ + tt) * PXW + ch];
  }
  float o = acc / (1.f + __expf(-acc));
  xbc[(size_t)bt * CONVD + ch] = o;
}

// ------- dt softplus + per-chunk cumsum(dt*A): parallel 2-phase scan --------
__global__ __launch_bounds__(256) void k_dt(
    const float* __restrict__ projx, const float* __restrict__ dtb,
    const float* __restrict__ alog, float* __restrict__ dtv,
    float* __restrict__ dac) {
  const int bc = blockIdx.x;  // 16 = b*8+c
  const int b = bc >> 3, c = bc & 7;
  const int h = threadIdx.x & 63, q = threadIdx.x >> 6;
  const float bias = dtb[h];
  const float Ah = -__expf(alog[h]);
  const size_t base = (size_t)b * LQ + c * CHK + q * 64;
  float vals[64];
  float part = 0.f;
#pragma unroll
  for (int j = 0; j < 64; j++) {
    float raw = projx[(base + j) * PXW + CONVD + h] + bias;
    float dt = raw > 20.f ? raw : log1pf(__expf(raw));
    vals[j] = dt;
    dtv[(base + j) * NH + h] = dt;
    part += dt;
  }
  __shared__ float partials[4][64];
  partials[q][h] = part;
  __syncthreads();
  float cum = 0.f;
  for (int qq = 0; qq < q; qq++) cum += partials[qq][h];
  cum *= Ah;
#pragma unroll
  for (int j = 0; j < 64; j++) {
    cum += vals[j] * Ah;
    dac[(base + j) * NH + h] = cum;
  }
}

// ---------------- CB[t][s] = sum_n C[t][n]*B[s][n] per (b,c) ----------------
__global__ __launch_bounds__(256) void k_cb(const float* __restrict__ xbc,
                                            float* __restrict__ cbuf) {
  const int q = blockIdx.x;   // 4 quadrants
  const int bc = blockIdx.y;  // 16
  const int b = bc >> 3, c = bc & 7;
  const int qt = q >> 1, qs = q & 1;
  __shared__ unsigned short lC[128][136];
  __shared__ unsigned short lB[128][136];
  const int tid = threadIdx.x, lane = tid & 63, w = tid >> 6;
  {
    int r = tid >> 1, hf = tid & 1;
    size_t rowc = (size_t)b * LQ + c * CHK + qt * 128 + r;
    const float* crp = xbc + rowc * CONVD + DIN + NST + hf * 64;
    size_t rowb = (size_t)b * LQ + c * CHK + qs * 128 + r;
    const float* brp = xbc + rowb * CONVD + DIN + hf * 64;
#pragma unroll
    for (int n = 0; n < 64; n++) {
      lC[r][hf * 64 + n] = f2bu(crp[n]);
      lB[r][hf * 64 + n] = f2bu(brp[n]);
    }
  }
  __syncthreads();
  const int wr = (w >> 1) * 64, wc = (w & 1) * 64;
  f32x4 acc[4][4] = {};
#pragma unroll
  for (int kk = 0; kk < 128; kk += 32) {
    short8 a[4], bb[4];
    const int ko = kk + ((lane >> 4) << 3);
#pragma unroll
    for (int i = 0; i < 4; i++) {
      a[i] = *reinterpret_cast<const short8*>(&lC[wr + i * 16 + (lane & 15)][ko]);
      bb[i] = *reinterpret_cast<const short8*>(&lB[wc + i * 16 + (lane & 15)][ko]);
    }
#pragma unroll
    for (int mi = 0; mi < 4; mi++)
#pragma unroll
      for (int ni = 0; ni < 4; ni++)
        acc[mi][ni] = mfma16(a[mi], bb[ni], acc[mi][ni]);
  }
  float* outp = cbuf + (size_t)bc * (CHK * CHK);
#pragma unroll
  for (int mi = 0; mi < 4; mi++) {
    const int t = qt * 128 + wr + mi * 16 + ((lane >> 4) << 2);
#pragma unroll
    for (int ni = 0; ni < 4; ni++) {
      const int s = qs * 128 + wc + ni * 16 + (lane & 15);
#pragma unroll
      for (int v = 0; v < 4; v++)
        outp[(size_t)(t + v) * CHK + s] = acc[mi][ni][v];
    }
  }
}

// ---------------- fused Y_diag + states per (b,c,h) -------------------------
__global__ __launch_bounds__(256) void k_diag(
    const float* __restrict__ xbc, const float* __restrict__ dtv,
    const float* __restrict__ dac, const float* __restrict__ cbuf,
    float* __restrict__ y, float* __restrict__ st) {
  const int h = blockIdx.x, c = blockIdx.y, b = blockIdx.z;
  const int cs = c * CHK;
  __shared__ unsigned short lXt[64][264];   // (p, s) x*dt, bf16
  __shared__ unsigned short lBt[128][264];  // (n, s) B*decay, bf16
  __shared__ unsigned short lS[256][40];    // (t, s-block32) masked S, bf16
  __shared__ float lda[256];
  const int tid = threadIdx.x, lane = tid & 63, w = tid >> 6;
  lda[tid] = dac[((size_t)b * LQ + cs + tid) * NH + h];
  __syncthreads();
  const float dalast = lda[255];
  {
    const int s = tid;
    const float* xrow = xbc + ((size_t)b * LQ + cs + s) * CONVD;
    const float dts = dtv[((size_t)b * LQ + cs + s) * NH + h];
    const f32x4* x4 = reinterpret_cast<const f32x4*>(xrow + h * HD);
#pragma unroll
    for (int p4 = 0; p4 < 16; p4++) {
      f32x4 v = x4[p4];
#pragma unroll
      for (int u = 0; u < 4; u++) lXt[p4 * 4 + u][s] = f2bu(v[u] * dts);
    }
    const float dec = __expf(dalast - lda[s]);
    const f32x4* b4 = reinterpret_cast<const f32x4*>(xrow + DIN);
#pragma unroll
    for (int n4 = 0; n4 < 32; n4++) {
      f32x4 v = b4[n4];
#pragma unroll
      for (int u = 0; u < 4; u++) lBt[n4 * 4 + u][s] = f2bu(v[u] * dec);
    }
  }
  __syncthreads();
  const float* cbp = cbuf + ((size_t)(b * NCH + c)) * (CHK * CHK);
  const float da_t = lda[tid];
  f32x4 accY[4][4] = {};
  f32x4 accS[4][2] = {};
  const int wn = w * 32;
  for (int sb = 0; sb < 8; sb++) {
    {
      const int t = tid;
      const f32x4* cr = reinterpret_cast<const f32x4*>(cbp + (size_t)t * CHK + sb * 32);
      f32x4 vv[8];
#pragma unroll
      for (int j4 = 0; j4 < 8; j4++) vv[j4] = cr[j4];
#pragma unroll
      for (int g = 0; g < 4; g++) {
        short8 pk;
#pragma unroll
        for (int e = 0; e < 8; e++) {
          const int j = g * 8 + e;
          const int s = sb * 32 + j;
          const float x = vv[j >> 2][j & 3];
          const float val = (s <= t) ? x * __expf(da_t - lda[s]) : 0.f;
          pk[e] = (short)f2bu(val);
        }
        *reinterpret_cast<short8*>(&lS[t][g * 8]) = pk;
      }
    }
    __syncthreads();
    short8 sf[4], xf[4], btf[2];
    const int ko = ((lane >> 4) << 3);
#pragma unroll
    for (int i = 0; i < 4; i++) {
      sf[i] = *reinterpret_cast<const short8*>(&lS[w * 64 + i * 16 + (lane & 15)][ko]);
      xf[i] = *reinterpret_cast<const short8*>(&lXt[i * 16 + (lane & 15)][sb * 32 + ko]);
    }
#pragma unroll
    for (int i = 0; i < 2; i++)
      btf[i] = *reinterpret_cast<const short8*>(&lBt[wn + i * 16 + (lane & 15)][sb * 32 + ko]);
#pragma unroll
    for (int mi = 0; mi < 4; mi++)
#pragma unroll
      for (int ni = 0; ni < 4; ni++)
        accY[mi][ni] = mfma16(sf[mi], xf[ni], accY[mi][ni]);
#pragma unroll
    for (int mi = 0; mi < 4; mi++)
#pragma unroll
      for (int nj = 0; nj < 2; nj++)
        accS[mi][nj] = mfma16(xf[mi], btf[nj], accS[mi][nj]);
    __syncthreads();
  }
#pragma unroll
  for (int mi = 0; mi < 4; mi++) {
    const int t = w * 64 + mi * 16 + ((lane >> 4) << 2);
#pragma unroll
    for (int ni = 0; ni < 4; ni++) {
      const int p = ni * 16 + (lane & 15);
#pragma unroll
      for (int v = 0; v < 4; v++)
        y[((size_t)b * LQ + cs + t + v) * DIN + h * HD + p] = accY[mi][ni][v];
    }
  }
  float* stp = st + ((size_t)((b * NCH + c) * NH + h)) * (HD * NST);
#pragma unroll
  for (int mi = 0; mi < 4; mi++) {
    const int p = mi * 16 + ((lane >> 4) << 2);
#pragma unroll
    for (int nj = 0; nj < 2; nj++) {
      const int n = wn + nj * 16 + (lane & 15);
#pragma unroll
      for (int v = 0; v < 4; v++)
        stp[(size_t)(p + v) * NST + n] = accS[mi][nj][v];
    }
  }
}

// ---------------- inter-chunk state scan ------------------------------------
__global__ void k_scan(const float* __restrict__ st, const float* __restrict__ dac,
                       float* __restrict__ pv) {
  const int h = blockIdx.x, b = blockIdx.y;
  const int tid = threadIdx.x;
  float P[32];
#pragma unroll
  for (int j = 0; j < 32; j++) P[j] = 0.f;
  for (int c = 0; c < NCH; c++) {
    const size_t base = ((size_t)((b * NCH + c) * NH + h)) * (HD * NST);
#pragma unroll
    for (int j = 0; j < 32; j++) pv[base + tid + 256 * j] = P[j];
    const float d = __expf(dac[((size_t)b * LQ + c * CHK + 255) * NH + h]);
#pragma unroll
    for (int j = 0; j < 32; j++) P[j] = P[j] * d + st[base + tid + 256 * j];
  }
}

// ---------------- Y_off + D*x accumulate into y -----------------------------
__global__ __launch_bounds__(256) void k_off(
    const float* __restrict__ xbc, const float* __restrict__ dac,
    const float* __restrict__ pv, const float* __restrict__ Dp,
    float* __restrict__ y) {
  const int h = blockIdx.x, c = blockIdx.y, b = blockIdx.z;
  const int cs = c * CHK;
  __shared__ unsigned short lC[256][136];  // (t, n)
  __shared__ unsigned short lP[64][136];   // (p, n)
  __shared__ float lda[256];
  const int tid = threadIdx.x, lane = tid & 63, w = tid >> 6;
  {
    const int s = tid;
    lda[s] = dac[((size_t)b * LQ + cs + s) * NH + h];
    const f32x4* cr = reinterpret_cast<const f32x4*>(
        xbc + ((size_t)b * LQ + cs + s) * CONVD + DIN + NST);
#pragma unroll
    for (int n4 = 0; n4 < 32; n4++) {
      f32x4 v = cr[n4];
#pragma unroll
      for (int u = 0; u < 4; u++) lC[s][n4 * 4 + u] = f2bu(v[u]);
    }
  }
  if (tid < 64) {
    const f32x4* pr = reinterpret_cast<const f32x4*>(
        pv + ((size_t)((b * NCH + c) * NH + h)) * (HD * NST) + (size_t)tid * NST);
#pragma unroll
    for (int n4 = 0; n4 < 32; n4++) {
      f32x4 v = pr[n4];
#pragma unroll
      for (int u = 0; u < 4; u++) lP[tid][n4 * 4 + u] = f2bu(v[u]);
    }
  }
  __syncthreads();
  f32x4 acc[4][4] = {};
#pragma unroll
  for (int kk = 0; kk < 128; kk += 32) {
    short8 a[4], bb[4];
    const int ko = kk + ((lane >> 4) << 3);
#pragma unroll
    for (int i = 0; i < 4; i++) {
      a[i] = *reinterpret_cast<const short8*>(&lC[w * 64 + i * 16 + (lane & 15)][ko]);
      bb[i] = *reinterpret_cast<const short8*>(&lP[i * 16 + (lane & 15)][ko]);
    }
#pragma unroll
    for (int mi = 0; mi < 4; mi++)
#pragma unroll
      for (int ni = 0; ni < 4; ni++)
        acc[mi][ni] = mfma16(a[mi], bb[ni], acc[mi][ni]);
  }
  const float Dh = Dp[h];
#pragma unroll
  for (int mi = 0; mi < 4; mi++) {
    const int t = w * 64 + mi * 16 + ((lane >> 4) << 2);
#pragma unroll
    for (int ni = 0; ni < 4; ni++) {
      const int p = ni * 16 + (lane & 15);
#pragma unroll
      for (int v = 0; v < 4; v++) {
        const int tt = t + v;
        const size_t row = (size_t)b * LQ + cs + tt;
        const float scale = __expf(lda[tt]);
        const float xval = xbc[row * CONVD + h * HD + p];
        const size_t yi = row * DIN + h * HD + p;
        y[yi] += scale * acc[mi][ni][v] + Dh * xval;
      }
    }
  }
}

// ---------------- gate*silu + RMSNorm -> bf16 -------------------------------
__global__ __launch_bounds__(256) void k_gatenorm(
    const float* __restrict__ y, const unsigned short* __restrict__ gateb,
    const float* __restrict__ nw, unsigned short* __restrict__ hgb) {
  const int r = blockIdx.x;
  const int tid = threadIdx.x;
  const float* yr = y + (size_t)r * DIN;
  const unsigned short* gr = gateb + (size_t)r * DIN;
  float hg[16];
  float ss = 0.f;
#pragma unroll
  for (int j = 0; j < 16; j++) {
    const int d = tid + 256 * j;
    const float g = __bfloat162float(__builtin_bit_cast(__hip_bfloat16, gr[d]));
    const float v = yr[d] * (g / (1.f + __expf(-g)));
    hg[j] = v;
    ss += v * v;
  }
#pragma unroll
  for (int o = 32; o > 0; o >>= 1) ss += __shfl_down(ss, o);
  __shared__ float red[4];
  if ((tid & 63) == 0) red[tid >> 6] = ss;
  __syncthreads();
  const float tot = red[0] + red[1] + red[2] + red[3];
  const float scale = rsqrtf(tot / (float)DIN + 1e-5f);
#pragma unroll
  for (int j = 0; j < 16; j++) {
    const int d = tid + 256 * j;
    hgb[(size_t)r * DIN + d] = f2bu(hg[j] * scale * nw[d]);
  }
}

extern "C" void kernel_launch(void* const* d_in, const int* in_sizes, int n_in,
                              void* d_out, int out_size, void* d_ws, size_t ws_size,
                              hipStream_t stream) {
  const float* hidden = (const float*)d_in[0];
  const float* w1 = (const float*)d_in[1];
  const float* cw = (const float*)d_in[2];
  const float* cb = (const float*)d_in[3];
  const float* dtb = (const float*)d_in[4];
  const float* alog = (const float*)d_in[5];
  const float* Dp = (const float*)d_in[6];
  const float* nw = (const float*)d_in[7];
  const float* w2 = (const float*)d_in[8];
  float* out = (float*)d_out;
  char* ws = (char*)d_ws;

  // Lifetime-aliased layout (stages S1 casts+GEMM1 / S2 conv+dt / S3 ssd / S4
  // gatenorm / S5 GEMM2). Peak live = 245.4 MB < ws.
  const size_t OFF_GATEB = 0;            // bf16 4096x4096   S1-S4
  const size_t OFF_XBC = 33554432;       // f32 4096x4352    S2-S3
  const size_t OFF_DTV = 104857600;      // f32 4096x64      S2-S3
  const size_t OFF_DAC = 105906176;      // f32 4096x64      S2-S3
  const size_t OFF_CB = 106954752;       // f32 16x256x256   S3
  const size_t OFF_Y = 111149056;        // f32 4096x4096    S3-S4
  const size_t OFF_ST = 178257920;       // f32 1024x64x128  S3
  const size_t OFF_PV = 211812352;       // f32 1024x64x128  S3
  const size_t OFF_PROJX = 111149056;    // f32 4096x4416    S1-S2 (aliases Y+ST head)
  const size_t OFF_HB = 183500800;       // bf16 4096x2048   S1 (aliases ST tail+)
  const size_t OFF_W1B = 200278016;      // bf16 8576x2048   S1 (aliases PV)
  const size_t OFF_W2B = 0;              // bf16 2048x4096   S5 (aliases GATEB)
  const size_t OFF_HGB = 33554432;       // bf16 4096x4096   S4-S5 (aliases XBC)
  const size_t NEED = 245366784;
  if (ws_size < NEED) {
    fprintf(stderr, "WS TOO SMALL: %zu < %zu\n", ws_size, NEED);
    return;
  }
  unsigned short* gateb = (unsigned short*)(ws + OFF_GATEB);
  float* xbc = (float*)(ws + OFF_XBC);
  float* dtv = (float*)(ws + OFF_DTV);
  float* dac = (float*)(ws + OFF_DAC);
  float* cbuf = (float*)(ws + OFF_CB);
  float* y = (float*)(ws + OFF_Y);
  float* st = (float*)(ws + OFF_ST);
  float* pv = (float*)(ws + OFF_PV);
  float* projx = (float*)(ws + OFF_PROJX);
  unsigned short* hb = (unsigned short*)(ws + OFF_HB);
  unsigned short* w1b = (unsigned short*)(ws + OFF_W1B);
  unsigned short* w2b = (unsigned short*)(ws + OFF_W2B);
  unsigned short* hgb = (unsigned short*)(ws + OFF_HGB);

  // S1
  k_cast_pad<<<4096, 256, 0, stream>>>(hidden, hb, (long)BL * DMODEL, (long)BL * DMODEL);
  k_cast_pad<<<8192, 256, 0, stream>>>(w1, w1b, (long)PROJD * DMODEL, (long)PROJ_PAD * DMODEL);
  k_gemm_bt<true><<<dim3(PROJ_PAD / 128, BL / 128), 256, 0, stream>>>(
      hb, w1b, nullptr, gateb, projx, PROJD, DMODEL);
  // S2
  k_conv_silu<<<dim3(17, BL), 256, 0, stream>>>(projx, cw, cb, xbc);
  k_dt<<<16, 256, 0, stream>>>(projx, dtb, alog, dtv, dac);
  // S3
  k_cb<<<dim3(4, 16), 256, 0, stream>>>(xbc, cbuf);
  k_diag<<<dim3(NH, NCH, BB), 256, 0, stream>>>(xbc, dtv, dac, cbuf, y, st);
  k_scan<<<dim3(NH, BB), 256, 0, stream>>>(st, dac, pv);
  k_off<<<dim3(NH, NCH, BB), 256, 0, stream>>>(xbc, dac, pv, Dp, y);
  // S4
  k_gatenorm<<<BL, 256, 0, stream>>>(y, gateb, nw, hgb);
  // S5
  k_cast_pad<<<8192, 256, 0, stream>>>(w2, w2b, (long)DMODEL * DIN, (long)DMODEL * DIN);
  k_gemm_bt<false><<<dim3(DMODEL / 128, BL / 128), 256, 0, stream>>>(
      hgb, w2b, out, nullptr, nullptr, DMODEL, DIN);
}

// Round 4
// 711.671 us; speedup vs baseline: 1.1354x; 1.0453x over previous
//
#include <hip/hip_runtime.h>
#include <hip/hip_bf16.h>
#include <cstdio>

#define LQ 2048      // L
#define BB 2         // batch
#define BL 4096      // B*L rows
#define DMODEL 2048
#define DIN 4096
#define NH 64
#define HD 64
#define NST 128
#define CONVD 4352
#define PROJD 8512
#define PROJ_PAD 8576
#define PXW 4416     // projx width: CONVD + NH
#define CHK 256
#define NCH 8        // chunks per batch

typedef __attribute__((ext_vector_type(8))) short short8;
typedef __attribute__((ext_vector_type(4))) float f32x4;
typedef __attribute__((ext_vector_type(4))) unsigned int u32x4;

__device__ __forceinline__ unsigned short f2bu(float x) {
  __hip_bfloat16 h = __float2bfloat16(x);
  return __builtin_bit_cast(unsigned short, h);
}

__device__ __forceinline__ f32x4 mfma16(short8 a, short8 b, f32x4 c) {
  return __builtin_amdgcn_mfma_f32_16x16x32_bf16(a, b, c, 0, 0, 0);
}

#define GLD16(gptr, lptr)                                                  \
  __builtin_amdgcn_global_load_lds(                                        \
      (const __attribute__((address_space(1))) void*)(gptr),               \
      (__attribute__((address_space(3))) void*)(lptr), 16, 0, 0)

// ---------------- cast fp32 -> bf16 (with zero tail padding) ----------------
__global__ void k_cast_pad(const float* __restrict__ in, unsigned short* __restrict__ out,
                           long n, long ntot) {
  long i = (long)blockIdx.x * blockDim.x + threadIdx.x;
  long stride = (long)gridDim.x * blockDim.x;
  for (; i < ntot; i += stride)
    out[i] = (i < n) ? f2bu(in[i]) : (unsigned short)0;
}

// ---- bf16 GEMM: C(M,Nreal) = A(M,K) @ B(Npad,K)^T -------------------------
// m97 structure + T2 both-sides XOR swizzle: LDS dest linear (gld_lds reqt),
// global source column-group pre-swizzled by (row&7), read side applies the
// same involution. row&7 == (tid>>3)&7 (staging) == lane&7 (read), so the
// swizzle is a single XOR per thread.
// SPLIT=true: cols [0,DIN) -> bf16 gateb; cols [DIN,PROJD) -> fp32 projx.
template <bool SPLIT>
__global__ __launch_bounds__(256) void k_gemm_bt(
    const unsigned short* __restrict__ A, const unsigned short* __restrict__ Bw,
    float* __restrict__ C, unsigned short* __restrict__ gateb,
    float* __restrict__ projx, int Nreal, int K) {
  __shared__ unsigned short lA[128][64];
  __shared__ unsigned short lB[128][64];
  const int tid = threadIdx.x;
  const int lane = tid & 63, w = tid >> 6;
  // XCD-aware bijective swizzle (nwg % 8 == 0 for both call sites)
  const int gx = gridDim.x;
  const int nwg = gx * gridDim.y;
  const int bid = blockIdx.y * gx + blockIdx.x;
  const int qq = nwg >> 3;
  const int swz = (bid & 7) * qq + (bid >> 3);
  const int m0 = (swz / gx) * 128, n0 = (swz % gx) * 128;
  const int wr = (w >> 1) * 64, wc = (w & 1) * 64;
  // staging coords: thread -> (row, col-group) within 128x64 tile.
  // LDS dest is LINEAR (lane i -> base + i*16); global col-group is swizzled.
  const int sr = tid >> 3;
  const int sdst = (tid & 7) * 8;                              // linear LDS col
  const int ssrc = ((tid & 7) ^ ((tid >> 3) & 7)) * 8;         // swizzled gmem col
  f32x4 acc[4][4] = {};
  for (int kb = 0; kb < K; kb += 64) {
#pragma unroll
    for (int i = 0; i < 4; i++) {
      const int r = sr + i * 32;  // r&7 == (tid>>3)&7 (32 = 0 mod 8)
      GLD16(A + (size_t)(m0 + r) * K + kb + ssrc, &lA[r][sdst]);
      GLD16(Bw + (size_t)(n0 + r) * K + kb + ssrc, &lB[r][sdst]);
    }
    __syncthreads();
#pragma unroll
    for (int kk = 0; kk < 64; kk += 32) {
      short8 af[4], bf[4];
      // logical col-group = (kk>>3)+(lane>>4); row&7 == lane&7 on all frags
      const int cg = ((((kk >> 3) + (lane >> 4)) ^ (lane & 7)) << 3);
#pragma unroll
      for (int i = 0; i < 4; i++) {
        af[i] = *reinterpret_cast<const short8*>(&lA[wr + i * 16 + (lane & 15)][cg]);
        bf[i] = *reinterpret_cast<const short8*>(&lB[wc + i * 16 + (lane & 15)][cg]);
      }
#pragma unroll
      for (int mi = 0; mi < 4; mi++)
#pragma unroll
        for (int ni = 0; ni < 4; ni++)
          acc[mi][ni] = mfma16(af[mi], bf[ni], acc[mi][ni]);
    }
    __syncthreads();
  }
#pragma unroll
  for (int mi = 0; mi < 4; mi++) {
    const int row = m0 + wr + mi * 16 + ((lane >> 4) << 2);
#pragma unroll
    for (int ni = 0; ni < 4; ni++) {
      const int col = n0 + wc + ni * 16 + (lane & 15);
      if (SPLIT) {
        if (col < DIN) {
#pragma unroll
          for (int v = 0; v < 4; v++)
            gateb[(size_t)(row + v) * DIN + col] = f2bu(acc[mi][ni][v]);
        } else if (col < PROJD) {
#pragma unroll
          for (int v = 0; v < 4; v++)
            projx[(size_t)(row + v) * PXW + (col - DIN)] = acc[mi][ni][v];
        }
      } else {
        if (col < Nreal) {
#pragma unroll
          for (int v = 0; v < 4; v++)
            C[(size_t)(row + v) * Nreal + col] = acc[mi][ni][v];
        }
      }
    }
  }
}

// ---------------- causal depthwise conv (K=4) + SiLU ------------------------
__global__ __launch_bounds__(256) void k_conv_silu(
    const float* __restrict__ projx, const float* __restrict__ cw,
    const float* __restrict__ cb, float* __restrict__ xbc) {
  const int ch = blockIdx.x * 256 + threadIdx.x;  // 17*256 = 4352 exact
  const int bt = blockIdx.y;
  const int b = bt >> 11, t = bt & 2047;
  float acc = cb[ch];
#pragma unroll
  for (int i = 0; i < 4; i++) {
    int tt = t - 3 + i;
    if (tt >= 0)
      acc += cw[ch * 4 + i] * projx[((size_t)b * LQ + tt) * PXW + ch];
  }
  float o = acc / (1.f + __expf(-acc));
  xbc[(size_t)bt * CONVD + ch] = o;
}

// ------- dt softplus + per-chunk cumsum(dt*A): parallel 2-phase scan --------
__global__ __launch_bounds__(256) void k_dt(
    const float* __restrict__ projx, const float* __restrict__ dtb,
    const float* __restrict__ alog, float* __restrict__ dtv,
    float* __restrict__ dac) {
  const int bc = blockIdx.x;  // 16 = b*8+c
  const int b = bc >> 3, c = bc & 7;
  const int h = threadIdx.x & 63, q = threadIdx.x >> 6;
  const float bias = dtb[h];
  const float Ah = -__expf(alog[h]);
  const size_t base = (size_t)b * LQ + c * CHK + q * 64;
  float vals[64];
  float part = 0.f;
#pragma unroll
  for (int j = 0; j < 64; j++) {
    float raw = projx[(base + j) * PXW + CONVD + h] + bias;
    float dt = raw > 20.f ? raw : log1pf(__expf(raw));
    vals[j] = dt;
    dtv[(base + j) * NH + h] = dt;
    part += dt;
  }
  __shared__ float partials[4][64];
  partials[q][h] = part;
  __syncthreads();
  float cum = 0.f;
  for (int qq = 0; qq < q; qq++) cum += partials[qq][h];
  cum *= Ah;
#pragma unroll
  for (int j = 0; j < 64; j++) {
    cum += vals[j] * Ah;
    dac[(base + j) * NH + h] = cum;
  }
}

// ---------------- CB[t][s] = sum_n C[t][n]*B[s][n] per (b,c) ----------------
__global__ __launch_bounds__(256) void k_cb(const float* __restrict__ xbc,
                                            float* __restrict__ cbuf) {
  const int q = blockIdx.x;   // 4 quadrants
  const int bc = blockIdx.y;  // 16
  const int b = bc >> 3, c = bc & 7;
  const int qt = q >> 1, qs = q & 1;
  __shared__ unsigned short lC[128][136];
  __shared__ unsigned short lB[128][136];
  const int tid = threadIdx.x, lane = tid & 63, w = tid >> 6;
  {
    int r = tid >> 1, hf = tid & 1;
    size_t rowc = (size_t)b * LQ + c * CHK + qt * 128 + r;
    const float* crp = xbc + rowc * CONVD + DIN + NST + hf * 64;
    size_t rowb = (size_t)b * LQ + c * CHK + qs * 128 + r;
    const float* brp = xbc + rowb * CONVD + DIN + hf * 64;
#pragma unroll
    for (int n = 0; n < 64; n++) {
      lC[r][hf * 64 + n] = f2bu(crp[n]);
      lB[r][hf * 64 + n] = f2bu(brp[n]);
    }
  }
  __syncthreads();
  const int wr = (w >> 1) * 64, wc = (w & 1) * 64;
  f32x4 acc[4][4] = {};
#pragma unroll
  for (int kk = 0; kk < 128; kk += 32) {
    short8 a[4], bb[4];
    const int ko = kk + ((lane >> 4) << 3);
#pragma unroll
    for (int i = 0; i < 4; i++) {
      a[i] = *reinterpret_cast<const short8*>(&lC[wr + i * 16 + (lane & 15)][ko]);
      bb[i] = *reinterpret_cast<const short8*>(&lB[wc + i * 16 + (lane & 15)][ko]);
    }
#pragma unroll
    for (int mi = 0; mi < 4; mi++)
#pragma unroll
      for (int ni = 0; ni < 4; ni++)
        acc[mi][ni] = mfma16(a[mi], bb[ni], acc[mi][ni]);
  }
  float* outp = cbuf + (size_t)bc * (CHK * CHK);
#pragma unroll
  for (int mi = 0; mi < 4; mi++) {
    const int t = qt * 128 + wr + mi * 16 + ((lane >> 4) << 2);
#pragma unroll
    for (int ni = 0; ni < 4; ni++) {
      const int s = qs * 128 + wc + ni * 16 + (lane & 15);
#pragma unroll
      for (int v = 0; v < 4; v++)
        outp[(size_t)(t + v) * CHK + s] = acc[mi][ni][v];
    }
  }
}

// ---------------- fused Y_diag + states per (b,c,h) -------------------------
__global__ __launch_bounds__(256) void k_diag(
    const float* __restrict__ xbc, const float* __restrict__ dtv,
    const float* __restrict__ dac, const float* __restrict__ cbuf,
    float* __restrict__ y, float* __restrict__ st) {
  const int h = blockIdx.x, c = blockIdx.y, b = blockIdx.z;
  const int cs = c * CHK;
  __shared__ unsigned short lXt[64][264];   // (p, s) x*dt, bf16
  __shared__ unsigned short lBt[128][264];  // (n, s) B*decay, bf16
  __shared__ unsigned short lS[256][40];    // (t, s-block32) masked S, bf16
  __shared__ float lda[256];
  const int tid = threadIdx.x, lane = tid & 63, w = tid >> 6;
  lda[tid] = dac[((size_t)b * LQ + cs + tid) * NH + h];
  __syncthreads();
  const float dalast = lda[255];
  {
    const int s = tid;
    const float* xrow = xbc + ((size_t)b * LQ + cs + s) * CONVD;
    const float dts = dtv[((size_t)b * LQ + cs + s) * NH + h];
    const f32x4* x4 = reinterpret_cast<const f32x4*>(xrow + h * HD);
#pragma unroll
    for (int p4 = 0; p4 < 16; p4++) {
      f32x4 v = x4[p4];
#pragma unroll
      for (int u = 0; u < 4; u++) lXt[p4 * 4 + u][s] = f2bu(v[u] * dts);
    }
    const float dec = __expf(dalast - lda[s]);
    const f32x4* b4 = reinterpret_cast<const f32x4*>(xrow + DIN);
#pragma unroll
    for (int n4 = 0; n4 < 32; n4++) {
      f32x4 v = b4[n4];
#pragma unroll
      for (int u = 0; u < 4; u++) lBt[n4 * 4 + u][s] = f2bu(v[u] * dec);
    }
  }
  __syncthreads();
  const float* cbp = cbuf + ((size_t)(b * NCH + c)) * (CHK * CHK);
  const float da_t = lda[tid];
  f32x4 accY[4][4] = {};
  f32x4 accS[4][2] = {};
  const int wn = w * 32;
  for (int sb = 0; sb < 8; sb++) {
    {
      const int t = tid;
      const f32x4* cr = reinterpret_cast<const f32x4*>(cbp + (size_t)t * CHK + sb * 32);
      f32x4 vv[8];
#pragma unroll
      for (int j4 = 0; j4 < 8; j4++) vv[j4] = cr[j4];
#pragma unroll
      for (int g = 0; g < 4; g++) {
        short8 pk;
#pragma unroll
        for (int e = 0; e < 8; e++) {
          const int j = g * 8 + e;
          const int s = sb * 32 + j;
          const float x = vv[j >> 2][j & 3];
          const float val = (s <= t) ? x * __expf(da_t - lda[s]) : 0.f;
          pk[e] = (short)f2bu(val);
        }
        *reinterpret_cast<short8*>(&lS[t][g * 8]) = pk;
      }
    }
    __syncthreads();
    short8 sf[4], xf[4], btf[2];
    const int ko = ((lane >> 4) << 3);
#pragma unroll
    for (int i = 0; i < 4; i++) {
      sf[i] = *reinterpret_cast<const short8*>(&lS[w * 64 + i * 16 + (lane & 15)][ko]);
      xf[i] = *reinterpret_cast<const short8*>(&lXt[i * 16 + (lane & 15)][sb * 32 + ko]);
    }
#pragma unroll
    for (int i = 0; i < 2; i++)
      btf[i] = *reinterpret_cast<const short8*>(&lBt[wn + i * 16 + (lane & 15)][sb * 32 + ko]);
#pragma unroll
    for (int mi = 0; mi < 4; mi++)
#pragma unroll
      for (int ni = 0; ni < 4; ni++)
        accY[mi][ni] = mfma16(sf[mi], xf[ni], accY[mi][ni]);
#pragma unroll
    for (int mi = 0; mi < 4; mi++)
#pragma unroll
      for (int nj = 0; nj < 2; nj++)
        accS[mi][nj] = mfma16(xf[mi], btf[nj], accS[mi][nj]);
    __syncthreads();
  }
#pragma unroll
  for (int mi = 0; mi < 4; mi++) {
    const int t = w * 64 + mi * 16 + ((lane >> 4) << 2);
#pragma unroll
    for (int ni = 0; ni < 4; ni++) {
      const int p = ni * 16 + (lane & 15);
#pragma unroll
      for (int v = 0; v < 4; v++)
        y[((size_t)b * LQ + cs + t + v) * DIN + h * HD + p] = accY[mi][ni][v];
    }
  }
  float* stp = st + ((size_t)((b * NCH + c) * NH + h)) * (HD * NST);
#pragma unroll
  for (int mi = 0; mi < 4; mi++) {
    const int p = mi * 16 + ((lane >> 4) << 2);
#pragma unroll
    for (int nj = 0; nj < 2; nj++) {
      const int n = wn + nj * 16 + (lane & 15);
#pragma unroll
      for (int v = 0; v < 4; v++)
        stp[(size_t)(p + v) * NST + n] = accS[mi][nj][v];
    }
  }
}

// ---------------- inter-chunk state scan ------------------------------------
__global__ void k_scan(const float* __restrict__ st, const float* __restrict__ dac,
                       float* __restrict__ pv) {
  const int h = blockIdx.x, b = blockIdx.y;
  const int tid = threadIdx.x;
  float P[32];
#pragma unroll
  for (int j = 0; j < 32; j++) P[j] = 0.f;
  for (int c = 0; c < NCH; c++) {
    const size_t base = ((size_t)((b * NCH + c) * NH + h)) * (HD * NST);
#pragma unroll
    for (int j = 0; j < 32; j++) pv[base + tid + 256 * j] = P[j];
    const float d = __expf(dac[((size_t)b * LQ + c * CHK + 255) * NH + h]);
#pragma unroll
    for (int j = 0; j < 32; j++) P[j] = P[j] * d + st[base + tid + 256 * j];
  }
}

// ---------------- Y_off + D*x accumulate into y -----------------------------
__global__ __launch_bounds__(256) void k_off(
    const float* __restrict__ xbc, const float* __restrict__ dac,
    const float* __restrict__ pv, const float* __restrict__ Dp,
    float* __restrict__ y) {
  const int h = blockIdx.x, c = blockIdx.y, b = blockIdx.z;
  const int cs = c * CHK;
  __shared__ unsigned short lC[256][136];  // (t, n)
  __shared__ unsigned short lP[64][136];   // (p, n)
  __shared__ float lda[256];
  const int tid = threadIdx.x, lane = tid & 63, w = tid >> 6;
  {
    const int s = tid;
    lda[s] = dac[((size_t)b * LQ + cs + s) * NH + h];
    const f32x4* cr = reinterpret_cast<const f32x4*>(
        xbc + ((size_t)b * LQ + cs + s) * CONVD + DIN + NST);
#pragma unroll
    for (int n4 = 0; n4 < 32; n4++) {
      f32x4 v = cr[n4];
#pragma unroll
      for (int u = 0; u < 4; u++) lC[s][n4 * 4 + u] = f2bu(v[u]);
    }
  }
  if (tid < 64) {
    const f32x4* pr = reinterpret_cast<const f32x4*>(
        pv + ((size_t)((b * NCH + c) * NH + h)) * (HD * NST) + (size_t)tid * NST);
#pragma unroll
    for (int n4 = 0; n4 < 32; n4++) {
      f32x4 v = pr[n4];
#pragma unroll
      for (int u = 0; u < 4; u++) lP[tid][n4 * 4 + u] = f2bu(v[u]);
    }
  }
  __syncthreads();
  f32x4 acc[4][4] = {};
#pragma unroll
  for (int kk = 0; kk < 128; kk += 32) {
    short8 a[4], bb[4];
    const int ko = kk + ((lane >> 4) << 3);
#pragma unroll
    for (int i = 0; i < 4; i++) {
      a[i] = *reinterpret_cast<const short8*>(&lC[w * 64 + i * 16 + (lane & 15)][ko]);
      bb[i] = *reinterpret_cast<const short8*>(&lP[i * 16 + (lane & 15)][ko]);
    }
#pragma unroll
    for (int mi = 0; mi < 4; mi++)
#pragma unroll
      for (int ni = 0; ni < 4; ni++)
        acc[mi][ni] = mfma16(a[mi], bb[ni], acc[mi][ni]);
  }
  const float Dh = Dp[h];
#pragma unroll
  for (int mi = 0; mi < 4; mi++) {
    const int t = w * 64 + mi * 16 + ((lane >> 4) << 2);
#pragma unroll
    for (int ni = 0; ni < 4; ni++) {
      const int p = ni * 16 + (lane & 15);
#pragma unroll
      for (int v = 0; v < 4; v++) {
        const int tt = t + v;
        const size_t row = (size_t)b * LQ + cs + tt;
        const float scale = __expf(lda[tt]);
        const float xval = xbc[row * CONVD + h * HD + p];
        const size_t yi = row * DIN + h * HD + p;
        y[yi] += scale * acc[mi][ni][v] + Dh * xval;
      }
    }
  }
}

// ---------------- gate*silu + RMSNorm -> bf16 -------------------------------
__global__ __launch_bounds__(256) void k_gatenorm(
    const float* __restrict__ y, const unsigned short* __restrict__ gateb,
    const float* __restrict__ nw, unsigned short* __restrict__ hgb) {
  const int r = blockIdx.x;
  const int tid = threadIdx.x;
  const float* yr = y + (size_t)r * DIN;
  const unsigned short* gr = gateb + (size_t)r * DIN;
  float hg[16];
  float ss = 0.f;
#pragma unroll
  for (int j = 0; j < 16; j++) {
    const int d = tid + 256 * j;
    const float g = __bfloat162float(__builtin_bit_cast(__hip_bfloat16, gr[d]));
    const float v = yr[d] * (g / (1.f + __expf(-g)));
    hg[j] = v;
    ss += v * v;
  }
#pragma unroll
  for (int o = 32; o > 0; o >>= 1) ss += __shfl_down(ss, o);
  __shared__ float red[4];
  if ((tid & 63) == 0) red[tid >> 6] = ss;
  __syncthreads();
  const float tot = red[0] + red[1] + red[2] + red[3];
  const float scale = rsqrtf(tot / (float)DIN + 1e-5f);
#pragma unroll
  for (int j = 0; j < 16; j++) {
    const int d = tid + 256 * j;
    hgb[(size_t)r * DIN + d] = f2bu(hg[j] * scale * nw[d]);
  }
}

extern "C" void kernel_launch(void* const* d_in, const int* in_sizes, int n_in,
                              void* d_out, int out_size, void* d_ws, size_t ws_size,
                              hipStream_t stream) {
  const float* hidden = (const float*)d_in[0];
  const float* w1 = (const float*)d_in[1];
  const float* cw = (const float*)d_in[2];
  const float* cb = (const float*)d_in[3];
  const float* dtb = (const float*)d_in[4];
  const float* alog = (const float*)d_in[5];
  const float* Dp = (const float*)d_in[6];
  const float* nw = (const float*)d_in[7];
  const float* w2 = (const float*)d_in[8];
  float* out = (float*)d_out;
  char* ws = (char*)d_ws;

  // Lifetime-aliased layout (stages S1 casts+GEMM1 / S2 conv+dt / S3 ssd / S4
  // gatenorm / S5 GEMM2). Peak live = 245.4 MB < ws.
  const size_t OFF_GATEB = 0;            // bf16 4096x4096   S1-S4
  const size_t OFF_XBC = 33554432;       // f32 4096x4352    S2-S3
  const size_t OFF_DTV = 104857600;      // f32 4096x64      S2-S3
  const size_t OFF_DAC = 105906176;      // f32 4096x64      S2-S3
  const size_t OFF_CB = 106954752;       // f32 16x256x256   S3
  const size_t OFF_Y = 111149056;        // f32 4096x4096    S3-S4
  const size_t OFF_ST = 178257920;       // f32 1024x64x128  S3
  const size_t OFF_PV = 211812352;       // f32 1024x64x128  S3
  const size_t OFF_PROJX = 111149056;    // f32 4096x4416    S1-S2 (aliases Y+ST head)
  const size_t OFF_HB = 183500800;       // bf16 4096x2048   S1 (aliases ST tail+)
  const size_t OFF_W1B = 200278016;      // bf16 8576x2048   S1 (aliases PV)
  const size_t OFF_W2B = 0;              // bf16 2048x4096   S5 (aliases GATEB)
  const size_t OFF_HGB = 33554432;       // bf16 4096x4096   S4-S5 (aliases XBC)
  const size_t NEED = 245366784;
  if (ws_size < NEED) {
    fprintf(stderr, "WS TOO SMALL: %zu < %zu\n", ws_size, NEED);
    return;
  }
  unsigned short* gateb = (unsigned short*)(ws + OFF_GATEB);
  float* xbc = (float*)(ws + OFF_XBC);
  float* dtv = (float*)(ws + OFF_DTV);
  float* dac = (float*)(ws + OFF_DAC);
  float* cbuf = (float*)(ws + OFF_CB);
  float* y = (float*)(ws + OFF_Y);
  float* st = (float*)(ws + OFF_ST);
  float* pv = (float*)(ws + OFF_PV);
  float* projx = (float*)(ws + OFF_PROJX);
  unsigned short* hb = (unsigned short*)(ws + OFF_HB);
  unsigned short* w1b = (unsigned short*)(ws + OFF_W1B);
  unsigned short* w2b = (unsigned short*)(ws + OFF_W2B);
  unsigned short* hgb = (unsigned short*)(ws + OFF_HGB);

  // S1
  k_cast_pad<<<4096, 256, 0, stream>>>(hidden, hb, (long)BL * DMODEL, (long)BL * DMODEL);
  k_cast_pad<<<8192, 256, 0, stream>>>(w1, w1b, (long)PROJD * DMODEL, (long)PROJ_PAD * DMODEL);
  k_gemm_bt<true><<<dim3(PROJ_PAD / 128, BL / 128), 256, 0, stream>>>(
      hb, w1b, nullptr, gateb, projx, PROJD, DMODEL);
  // S2
  k_conv_silu<<<dim3(17, BL), 256, 0, stream>>>(projx, cw, cb, xbc);
  k_dt<<<16, 256, 0, stream>>>(projx, dtb, alog, dtv, dac);
  // S3
  k_cb<<<dim3(4, 16), 256, 0, stream>>>(xbc, cbuf);
  k_diag<<<dim3(NH, NCH, BB), 256, 0, stream>>>(xbc, dtv, dac, cbuf, y, st);
  k_scan<<<dim3(NH, BB), 256, 0, stream>>>(st, dac, pv);
  k_off<<<dim3(NH, NCH, BB), 256, 0, stream>>>(xbc, dac, pv, Dp, y);
  // S4
  k_gatenorm<<<BL, 256, 0, stream>>>(y, gateb, nw, hgb);
  // S5
  k_cast_pad<<<8192, 256, 0, stream>>>(w2, w2b, (long)DMODEL * DIN, (long)DMODEL * DIN);
  k_gemm_bt<false><<<dim3(DMODEL / 128, BL / 128), 256, 0, stream>>>(
      hgb, w2b, out, nullptr, nullptr, DMODEL, DIN);
}

// Round 5
// 668.296 us; speedup vs baseline: 1.2091x; 1.0649x over previous
//
#include <hip/hip_runtime.h>
#include <hip/hip_bf16.h>
#include <cstdio>

#define LQ 2048      // L
#define BB 2         // batch
#define BL 4096      // B*L rows
#define DMODEL 2048
#define DIN 4096
#define NH 64
#define HD 64
#define NST 128
#define CONVD 4352
#define PROJD 8512
#define PROJ_PAD2 8704   // pad to 256 multiple for 256-tile GEMM1
#define PXW 4416     // projx width: CONVD + NH
#define CHK 256
#define NCH 8        // chunks per batch

typedef __attribute__((ext_vector_type(8))) short short8;
typedef __attribute__((ext_vector_type(4))) float f32x4;

__device__ __forceinline__ unsigned short f2bu(float x) {
  __hip_bfloat16 h = __float2bfloat16(x);
  return __builtin_bit_cast(unsigned short, h);
}

__device__ __forceinline__ f32x4 mfma16(short8 a, short8 b, f32x4 c) {
  return __builtin_amdgcn_mfma_f32_16x16x32_bf16(a, b, c, 0, 0, 0);
}

#define GLD16(gptr, lptr)                                                  \
  __builtin_amdgcn_global_load_lds(                                        \
      (const __attribute__((address_space(1))) void*)(gptr),               \
      (__attribute__((address_space(3))) void*)(lptr), 16, 0, 0)

// ---------------- cast fp32 -> bf16 (with zero tail padding) ----------------
__global__ void k_cast_pad(const float* __restrict__ in, unsigned short* __restrict__ out,
                           long n, long ntot) {
  long i = (long)blockIdx.x * blockDim.x + threadIdx.x;
  long stride = (long)gridDim.x * blockDim.x;
  for (; i < ntot; i += stride)
    out[i] = (i < n) ? f2bu(in[i]) : (unsigned short)0;
}

// swizzled fragment read from a [256][64] bf16 LDS tile (involution: cg ^= row&7)
__device__ __forceinline__ short8 rdfrag(const unsigned short (*mp)[64], int rowbase,
                                         int lane, int kh) {
  const int row = rowbase + (lane & 15);
  const int cg = (((kh << 2) + (lane >> 4)) ^ (lane & 7)) << 3;
  return *reinterpret_cast<const short8*>(&mp[row][cg]);
}

// ==== 256x256 8-phase GEMM: C(M,Nreal) = A(M,K) @ B(Npad,K)^T ==============
// 512 thr = 8 waves (2m x 4n), BK=64, double-buffered 128 KiB LDS,
// counted vmcnt (2 at tile entry, 4 mid-tile), raw barriers, T2 swizzle, T5.
// Stage order per tile: [A0,A2,B0,B1,B2,B3,A1,A3]; 2 rounds staged per phase.
template <bool SPLIT>
__global__ __launch_bounds__(512) void k_gemm256(
    const unsigned short* __restrict__ A, const unsigned short* __restrict__ Bw,
    float* __restrict__ C, unsigned short* __restrict__ gateb,
    float* __restrict__ projx, int Nreal, int K) {
  __shared__ unsigned short sh[2][2][256][64];  // [buf][A/B][row][col]
  const int tid = threadIdx.x;
  const int lane = tid & 63, w = tid >> 6;
  const int wm = w >> 2, wn2 = w & 3;
  const int gx = gridDim.x;
  const int nwg = gx * gridDim.y;
  const int bid = blockIdx.y * gx + blockIdx.x;
  const int qq = nwg >> 3;
  const int swz = (bid & 7) * qq + (bid >> 3);
  const int m0 = (swz / gx) * 256, n0 = (swz % gx) * 256;
  const int srow = tid >> 3;
  const int sdst = (tid & 7) * 8;                       // linear LDS col
  const int ssrc = ((tid & 7) ^ ((tid >> 3) & 7)) * 8;  // swizzled gmem col
  const unsigned short* Ab = A + (size_t)m0 * K;
  const unsigned short* Bb = Bw + (size_t)n0 * K;

#define ST(bf, mt, MP, r0, kk)                                             \
  GLD16(MP + (size_t)((r0) + srow) * K + (kk) + ssrc,                      \
        &sh[bf][mt][(r0) + srow][sdst])

  f32x4 acc[8][4] = {};
  const int nt = K >> 6;

  // prologue: stage tile 0 fully, in canonical round order
  ST(0, 0, Ab, 0, 0);   ST(0, 0, Ab, 128, 0);
  ST(0, 1, Bb, 0, 0);   ST(0, 1, Bb, 64, 0);
  ST(0, 1, Bb, 128, 0); ST(0, 1, Bb, 192, 0);
  ST(0, 0, Ab, 64, 0);  ST(0, 0, Ab, 192, 0);

#define DO_PHASE(P)                                                        \
  {                                                                        \
    const int rb = wm * 128 + (P) * 32;                                    \
    short8 a00 = rdfrag(sh[cur][0], rb, lane, 0);                          \
    short8 a01 = rdfrag(sh[cur][0], rb, lane, 1);                          \
    short8 a10 = rdfrag(sh[cur][0], rb + 16, lane, 0);                     \
    short8 a11 = rdfrag(sh[cur][0], rb + 16, lane, 1);                     \
    __builtin_amdgcn_s_setprio(1);                                         \
    _Pragma("unroll")                                                      \
    for (int nf = 0; nf < 4; nf++) {                                       \
      acc[2 * (P)][nf] = mfma16(a00, bfr[nf][0], acc[2 * (P)][nf]);        \
      acc[2 * (P)][nf] = mfma16(a01, bfr[nf][1], acc[2 * (P)][nf]);        \
      acc[2 * (P) + 1][nf] = mfma16(a10, bfr[nf][0], acc[2 * (P) + 1][nf]);\
      acc[2 * (P) + 1][nf] = mfma16(a11, bfr[nf][1], acc[2 * (P) + 1][nf]);\
    }                                                                      \
    __builtin_amdgcn_s_setprio(0);                                         \
  }

  for (int t = 0; t < nt; ++t) {
    const int cur = t & 1, nxt = cur ^ 1;
    const int kbn = (t + 1) << 6;
    const bool more = (t + 1 < nt);
    // entry: tile t rounds 0..5 (A0,A2,B0..B3) landed globally
    asm volatile("s_waitcnt vmcnt(2)" ::: "memory");
    __builtin_amdgcn_s_barrier();
    // ---- phase 0: stage A0,A2 of t+1; read all B frags + A mf0,1
    if (more) { ST(nxt, 0, Ab, 0, kbn); ST(nxt, 0, Ab, 128, kbn); }
    short8 bfr[4][2];
#pragma unroll
    for (int nf = 0; nf < 4; nf++) {
      bfr[nf][0] = rdfrag(sh[cur][1], wn2 * 64 + nf * 16, lane, 0);
      bfr[nf][1] = rdfrag(sh[cur][1], wn2 * 64 + nf * 16, lane, 1);
    }
    DO_PHASE(0)
    __builtin_amdgcn_s_barrier();
    // ---- phase 1: stage B0,B1 of t+1; A mf2,3
    if (more) { ST(nxt, 1, Bb, 0, kbn); ST(nxt, 1, Bb, 64, kbn); }
    DO_PHASE(1)
    // mid wait: tile t rounds A1,A3 landed globally
    if (more) asm volatile("s_waitcnt vmcnt(4)" ::: "memory");
    else      asm volatile("s_waitcnt vmcnt(0)" ::: "memory");
    __builtin_amdgcn_s_barrier();
    // ---- phase 2: stage B2,B3 of t+1; A mf4,5
    if (more) { ST(nxt, 1, Bb, 128, kbn); ST(nxt, 1, Bb, 192, kbn); }
    DO_PHASE(2)
    __builtin_amdgcn_s_barrier();
    // ---- phase 3: stage A1,A3 of t+1; A mf6,7
    if (more) { ST(nxt, 0, Ab, 64, kbn); ST(nxt, 0, Ab, 192, kbn); }
    DO_PHASE(3)
    // no trailing barrier: next tile's entry vmcnt+barrier covers it
  }
#undef DO_PHASE
#undef ST

  // epilogue
#pragma unroll
  for (int mf = 0; mf < 8; mf++) {
    const int row = m0 + wm * 128 + mf * 16 + ((lane >> 4) << 2);
#pragma unroll
    for (int nf = 0; nf < 4; nf++) {
      const int col = n0 + wn2 * 64 + nf * 16 + (lane & 15);
      if (SPLIT) {
        if (col < DIN) {
#pragma unroll
          for (int v = 0; v < 4; v++)
            gateb[(size_t)(row + v) * DIN + col] = f2bu(acc[mf][nf][v]);
        } else if (col < PROJD) {
#pragma unroll
          for (int v = 0; v < 4; v++)
            projx[(size_t)(row + v) * PXW + (col - DIN)] = acc[mf][nf][v];
        }
      } else {
        if (col < Nreal) {
#pragma unroll
          for (int v = 0; v < 4; v++)
            C[(size_t)(row + v) * Nreal + col] = acc[mf][nf][v];
        }
      }
    }
  }
}

// ---- 128x128 bf16 GEMM (proven R4 structure) — used for GEMM2 -------------
__global__ __launch_bounds__(256) void k_gemm_bt(
    const unsigned short* __restrict__ A, const unsigned short* __restrict__ Bw,
    float* __restrict__ C, int Nreal, int K) {
  __shared__ unsigned short lA[128][64];
  __shared__ unsigned short lB[128][64];
  const int tid = threadIdx.x;
  const int lane = tid & 63, w = tid >> 6;
  const int gx = gridDim.x;
  const int nwg = gx * gridDim.y;
  const int bid = blockIdx.y * gx + blockIdx.x;
  const int qq = nwg >> 3;
  const int swz = (bid & 7) * qq + (bid >> 3);
  const int m0 = (swz / gx) * 128, n0 = (swz % gx) * 128;
  const int wr = (w >> 1) * 64, wc = (w & 1) * 64;
  const int sr = tid >> 3;
  const int sdst = (tid & 7) * 8;
  const int ssrc = ((tid & 7) ^ ((tid >> 3) & 7)) * 8;
  f32x4 acc[4][4] = {};
  for (int kb = 0; kb < K; kb += 64) {
#pragma unroll
    for (int i = 0; i < 4; i++) {
      const int r = sr + i * 32;
      GLD16(A + (size_t)(m0 + r) * K + kb + ssrc, &lA[r][sdst]);
      GLD16(Bw + (size_t)(n0 + r) * K + kb + ssrc, &lB[r][sdst]);
    }
    __syncthreads();
#pragma unroll
    for (int kk = 0; kk < 64; kk += 32) {
      short8 af[4], bf[4];
      const int cg = ((((kk >> 3) + (lane >> 4)) ^ (lane & 7)) << 3);
#pragma unroll
      for (int i = 0; i < 4; i++) {
        af[i] = *reinterpret_cast<const short8*>(&lA[wr + i * 16 + (lane & 15)][cg]);
        bf[i] = *reinterpret_cast<const short8*>(&lB[wc + i * 16 + (lane & 15)][cg]);
      }
#pragma unroll
      for (int mi = 0; mi < 4; mi++)
#pragma unroll
        for (int ni = 0; ni < 4; ni++)
          acc[mi][ni] = mfma16(af[mi], bf[ni], acc[mi][ni]);
    }
    __syncthreads();
  }
#pragma unroll
  for (int mi = 0; mi < 4; mi++) {
    const int row = m0 + wr + mi * 16 + ((lane >> 4) << 2);
#pragma unroll
    for (int ni = 0; ni < 4; ni++) {
      const int col = n0 + wc + ni * 16 + (lane & 15);
      if (col < Nreal) {
#pragma unroll
        for (int v = 0; v < 4; v++)
          C[(size_t)(row + v) * Nreal + col] = acc[mi][ni][v];
      }
    }
  }
}

// ---------------- causal depthwise conv (K=4) + SiLU ------------------------
__global__ __launch_bounds__(256) void k_conv_silu(
    const float* __restrict__ projx, const float* __restrict__ cw,
    const float* __restrict__ cb, float* __restrict__ xbc) {
  const int ch = blockIdx.x * 256 + threadIdx.x;  // 17*256 = 4352 exact
  const int bt = blockIdx.y;
  const int b = bt >> 11, t = bt & 2047;
  float acc = cb[ch];
#pragma unroll
  for (int i = 0; i < 4; i++) {
    int tt = t - 3 + i;
    if (tt >= 0)
      acc += cw[ch * 4 + i] * projx[((size_t)b * LQ + tt) * PXW + ch];
  }
  float o = acc / (1.f + __expf(-acc));
  xbc[(size_t)bt * CONVD + ch] = o;
}

// ------- dt softplus + per-chunk cumsum(dt*A): parallel 2-phase scan --------
__global__ __launch_bounds__(256) void k_dt(
    const float* __restrict__ projx, const float* __restrict__ dtb,
    const float* __restrict__ alog, float* __restrict__ dtv,
    float* __restrict__ dac) {
  const int bc = blockIdx.x;  // 16 = b*8+c
  const int b = bc >> 3, c = bc & 7;
  const int h = threadIdx.x & 63, q = threadIdx.x >> 6;
  const float bias = dtb[h];
  const float Ah = -__expf(alog[h]);
  const size_t base = (size_t)b * LQ + c * CHK + q * 64;
  float vals[64];
  float part = 0.f;
#pragma unroll
  for (int j = 0; j < 64; j++) {
    float raw = projx[(base + j) * PXW + CONVD + h] + bias;
    float dt = raw > 20.f ? raw : log1pf(__expf(raw));
    vals[j] = dt;
    dtv[(base + j) * NH + h] = dt;
    part += dt;
  }
  __shared__ float partials[4][64];
  partials[q][h] = part;
  __syncthreads();
  float cum = 0.f;
  for (int qq = 0; qq < q; qq++) cum += partials[qq][h];
  cum *= Ah;
#pragma unroll
  for (int j = 0; j < 64; j++) {
    cum += vals[j] * Ah;
    dac[(base + j) * NH + h] = cum;
  }
}

// ---------------- CB[t][s] = sum_n C[t][n]*B[s][n] per (b,c) ----------------
__global__ __launch_bounds__(256) void k_cb(const float* __restrict__ xbc,
                                            float* __restrict__ cbuf) {
  const int q = blockIdx.x;   // 4 quadrants
  const int bc = blockIdx.y;  // 16
  const int b = bc >> 3, c = bc & 7;
  const int qt = q >> 1, qs = q & 1;
  __shared__ unsigned short lC[128][136];
  __shared__ unsigned short lB[128][136];
  const int tid = threadIdx.x, lane = tid & 63, w = tid >> 6;
  {
    int r = tid >> 1, hf = tid & 1;
    size_t rowc = (size_t)b * LQ + c * CHK + qt * 128 + r;
    const float* crp = xbc + rowc * CONVD + DIN + NST + hf * 64;
    size_t rowb = (size_t)b * LQ + c * CHK + qs * 128 + r;
    const float* brp = xbc + rowb * CONVD + DIN + hf * 64;
#pragma unroll
    for (int n = 0; n < 64; n++) {
      lC[r][hf * 64 + n] = f2bu(crp[n]);
      lB[r][hf * 64 + n] = f2bu(brp[n]);
    }
  }
  __syncthreads();
  const int wr = (w >> 1) * 64, wc = (w & 1) * 64;
  f32x4 acc[4][4] = {};
#pragma unroll
  for (int kk = 0; kk < 128; kk += 32) {
    short8 a[4], bb[4];
    const int ko = kk + ((lane >> 4) << 3);
#pragma unroll
    for (int i = 0; i < 4; i++) {
      a[i] = *reinterpret_cast<const short8*>(&lC[wr + i * 16 + (lane & 15)][ko]);
      bb[i] = *reinterpret_cast<const short8*>(&lB[wc + i * 16 + (lane & 15)][ko]);
    }
#pragma unroll
    for (int mi = 0; mi < 4; mi++)
#pragma unroll
      for (int ni = 0; ni < 4; ni++)
        acc[mi][ni] = mfma16(a[mi], bb[ni], acc[mi][ni]);
  }
  float* outp = cbuf + (size_t)bc * (CHK * CHK);
#pragma unroll
  for (int mi = 0; mi < 4; mi++) {
    const int t = qt * 128 + wr + mi * 16 + ((lane >> 4) << 2);
#pragma unroll
    for (int ni = 0; ni < 4; ni++) {
      const int s = qs * 128 + wc + ni * 16 + (lane & 15);
#pragma unroll
      for (int v = 0; v < 4; v++)
        outp[(size_t)(t + v) * CHK + s] = acc[mi][ni][v];
    }
  }
}

// ---------------- fused Y_diag + states per (b,c,h) -------------------------
__global__ __launch_bounds__(256) void k_diag(
    const float* __restrict__ xbc, const float* __restrict__ dtv,
    const float* __restrict__ dac, const float* __restrict__ cbuf,
    float* __restrict__ y, float* __restrict__ st) {
  const int h = blockIdx.x, c = blockIdx.y, b = blockIdx.z;
  const int cs = c * CHK;
  __shared__ unsigned short lXt[64][264];   // (p, s) x*dt, bf16
  __shared__ unsigned short lBt[128][264];  // (n, s) B*decay, bf16
  __shared__ unsigned short lS[256][40];    // (t, s-block32) masked S, bf16
  __shared__ float lda[256];
  const int tid = threadIdx.x, lane = tid & 63, w = tid >> 6;
  lda[tid] = dac[((size_t)b * LQ + cs + tid) * NH + h];
  __syncthreads();
  const float dalast = lda[255];
  {
    const int s = tid;
    const float* xrow = xbc + ((size_t)b * LQ + cs + s) * CONVD;
    const float dts = dtv[((size_t)b * LQ + cs + s) * NH + h];
    const f32x4* x4 = reinterpret_cast<const f32x4*>(xrow + h * HD);
#pragma unroll
    for (int p4 = 0; p4 < 16; p4++) {
      f32x4 v = x4[p4];
#pragma unroll
      for (int u = 0; u < 4; u++) lXt[p4 * 4 + u][s] = f2bu(v[u] * dts);
    }
    const float dec = __expf(dalast - lda[s]);
    const f32x4* b4 = reinterpret_cast<const f32x4*>(xrow + DIN);
#pragma unroll
    for (int n4 = 0; n4 < 32; n4++) {
      f32x4 v = b4[n4];
#pragma unroll
      for (int u = 0; u < 4; u++) lBt[n4 * 4 + u][s] = f2bu(v[u] * dec);
    }
  }
  __syncthreads();
  const float* cbp = cbuf + ((size_t)(b * NCH + c)) * (CHK * CHK);
  const float da_t = lda[tid];
  f32x4 accY[4][4] = {};
  f32x4 accS[4][2] = {};
  const int wn = w * 32;
  for (int sb = 0; sb < 8; sb++) {
    {
      const int t = tid;
      const f32x4* cr = reinterpret_cast<const f32x4*>(cbp + (size_t)t * CHK + sb * 32);
      f32x4 vv[8];
#pragma unroll
      for (int j4 = 0; j4 < 8; j4++) vv[j4] = cr[j4];
#pragma unroll
      for (int g = 0; g < 4; g++) {
        short8 pk;
#pragma unroll
        for (int e = 0; e < 8; e++) {
          const int j = g * 8 + e;
          const int s = sb * 32 + j;
          const float x = vv[j >> 2][j & 3];
          const float val = (s <= t) ? x * __expf(da_t - lda[s]) : 0.f;
          pk[e] = (short)f2bu(val);
        }
        *reinterpret_cast<short8*>(&lS[t][g * 8]) = pk;
      }
    }
    __syncthreads();
    short8 sf[4], xf[4], btf[2];
    const int ko = ((lane >> 4) << 3);
#pragma unroll
    for (int i = 0; i < 4; i++) {
      sf[i] = *reinterpret_cast<const short8*>(&lS[w * 64 + i * 16 + (lane & 15)][ko]);
      xf[i] = *reinterpret_cast<const short8*>(&lXt[i * 16 + (lane & 15)][sb * 32 + ko]);
    }
#pragma unroll
    for (int i = 0; i < 2; i++)
      btf[i] = *reinterpret_cast<const short8*>(&lBt[wn + i * 16 + (lane & 15)][sb * 32 + ko]);
#pragma unroll
    for (int mi = 0; mi < 4; mi++)
#pragma unroll
      for (int ni = 0; ni < 4; ni++)
        accY[mi][ni] = mfma16(sf[mi], xf[ni], accY[mi][ni]);
#pragma unroll
    for (int mi = 0; mi < 4; mi++)
#pragma unroll
      for (int nj = 0; nj < 2; nj++)
        accS[mi][nj] = mfma16(xf[mi], btf[nj], accS[mi][nj]);
    __syncthreads();
  }
#pragma unroll
  for (int mi = 0; mi < 4; mi++) {
    const int t = w * 64 + mi * 16 + ((lane >> 4) << 2);
#pragma unroll
    for (int ni = 0; ni < 4; ni++) {
      const int p = ni * 16 + (lane & 15);
#pragma unroll
      for (int v = 0; v < 4; v++)
        y[((size_t)b * LQ + cs + t + v) * DIN + h * HD + p] = accY[mi][ni][v];
    }
  }
  float* stp = st + ((size_t)((b * NCH + c) * NH + h)) * (HD * NST);
#pragma unroll
  for (int mi = 0; mi < 4; mi++) {
    const int p = mi * 16 + ((lane >> 4) << 2);
#pragma unroll
    for (int nj = 0; nj < 2; nj++) {
      const int n = wn + nj * 16 + (lane & 15);
#pragma unroll
      for (int v = 0; v < 4; v++)
        stp[(size_t)(p + v) * NST + n] = accS[mi][nj][v];
    }
  }
}

// ---------------- inter-chunk state scan ------------------------------------
__global__ void k_scan(const float* __restrict__ st, const float* __restrict__ dac,
                       float* __restrict__ pv) {
  const int h = blockIdx.x, b = blockIdx.y;
  const int tid = threadIdx.x;
  float P[32];
#pragma unroll
  for (int j = 0; j < 32; j++) P[j] = 0.f;
  for (int c = 0; c < NCH; c++) {
    const size_t base = ((size_t)((b * NCH + c) * NH + h)) * (HD * NST);
#pragma unroll
    for (int j = 0; j < 32; j++) pv[base + tid + 256 * j] = P[j];
    const float d = __expf(dac[((size_t)b * LQ + c * CHK + 255) * NH + h]);
#pragma unroll
    for (int j = 0; j < 32; j++) P[j] = P[j] * d + st[base + tid + 256 * j];
  }
}

// ---------------- Y_off + D*x accumulate into y -----------------------------
__global__ __launch_bounds__(256) void k_off(
    const float* __restrict__ xbc, const float* __restrict__ dac,
    const float* __restrict__ pv, const float* __restrict__ Dp,
    float* __restrict__ y) {
  const int h = blockIdx.x, c = blockIdx.y, b = blockIdx.z;
  const int cs = c * CHK;
  __shared__ unsigned short lC[256][136];  // (t, n)
  __shared__ unsigned short lP[64][136];   // (p, n)
  __shared__ float lda[256];
  const int tid = threadIdx.x, lane = tid & 63, w = tid >> 6;
  {
    const int s = tid;
    lda[s] = dac[((size_t)b * LQ + cs + s) * NH + h];
    const f32x4* cr = reinterpret_cast<const f32x4*>(
        xbc + ((size_t)b * LQ + cs + s) * CONVD + DIN + NST);
#pragma unroll
    for (int n4 = 0; n4 < 32; n4++) {
      f32x4 v = cr[n4];
#pragma unroll
      for (int u = 0; u < 4; u++) lC[s][n4 * 4 + u] = f2bu(v[u]);
    }
  }
  if (tid < 64) {
    const f32x4* pr = reinterpret_cast<const f32x4*>(
        pv + ((size_t)((b * NCH + c) * NH + h)) * (HD * NST) + (size_t)tid * NST);
#pragma unroll
    for (int n4 = 0; n4 < 32; n4++) {
      f32x4 v = pr[n4];
#pragma unroll
      for (int u = 0; u < 4; u++) lP[tid][n4 * 4 + u] = f2bu(v[u]);
    }
  }
  __syncthreads();
  f32x4 acc[4][4] = {};
#pragma unroll
  for (int kk = 0; kk < 128; kk += 32) {
    short8 a[4], bb[4];
    const int ko = kk + ((lane >> 4) << 3);
#pragma unroll
    for (int i = 0; i < 4; i++) {
      a[i] = *reinterpret_cast<const short8*>(&lC[w * 64 + i * 16 + (lane & 15)][ko]);
      bb[i] = *reinterpret_cast<const short8*>(&lP[i * 16 + (lane & 15)][ko]);
    }
#pragma unroll
    for (int mi = 0; mi < 4; mi++)
#pragma unroll
      for (int ni = 0; ni < 4; ni++)
        acc[mi][ni] = mfma16(a[mi], bb[ni], acc[mi][ni]);
  }
  const float Dh = Dp[h];
#pragma unroll
  for (int mi = 0; mi < 4; mi++) {
    const int t = w * 64 + mi * 16 + ((lane >> 4) << 2);
#pragma unroll
    for (int ni = 0; ni < 4; ni++) {
      const int p = ni * 16 + (lane & 15);
#pragma unroll
      for (int v = 0; v < 4; v++) {
        const int tt = t + v;
        const size_t row = (size_t)b * LQ + cs + tt;
        const float scale = __expf(lda[tt]);
        const float xval = xbc[row * CONVD + h * HD + p];
        const size_t yi = row * DIN + h * HD + p;
        y[yi] += scale * acc[mi][ni][v] + Dh * xval;
      }
    }
  }
}

// ---------------- gate*silu + RMSNorm -> bf16 -------------------------------
__global__ __launch_bounds__(256) void k_gatenorm(
    const float* __restrict__ y, const unsigned short* __restrict__ gateb,
    const float* __restrict__ nw, unsigned short* __restrict__ hgb) {
  const int r = blockIdx.x;
  const int tid = threadIdx.x;
  const float* yr = y + (size_t)r * DIN;
  const unsigned short* gr = gateb + (size_t)r * DIN;
  float hg[16];
  float ss = 0.f;
#pragma unroll
  for (int j = 0; j < 16; j++) {
    const int d = tid + 256 * j;
    const float g = __bfloat162float(__builtin_bit_cast(__hip_bfloat16, gr[d]));
    const float v = yr[d] * (g / (1.f + __expf(-g)));
    hg[j] = v;
    ss += v * v;
  }
#pragma unroll
  for (int o = 32; o > 0; o >>= 1) ss += __shfl_down(ss, o);
  __shared__ float red[4];
  if ((tid & 63) == 0) red[tid >> 6] = ss;
  __syncthreads();
  const float tot = red[0] + red[1] + red[2] + red[3];
  const float scale = rsqrtf(tot / (float)DIN + 1e-5f);
#pragma unroll
  for (int j = 0; j < 16; j++) {
    const int d = tid + 256 * j;
    hgb[(size_t)r * DIN + d] = f2bu(hg[j] * scale * nw[d]);
  }
}

extern "C" void kernel_launch(void* const* d_in, const int* in_sizes, int n_in,
                              void* d_out, int out_size, void* d_ws, size_t ws_size,
                              hipStream_t stream) {
  const float* hidden = (const float*)d_in[0];
  const float* w1 = (const float*)d_in[1];
  const float* cw = (const float*)d_in[2];
  const float* cb = (const float*)d_in[3];
  const float* dtb = (const float*)d_in[4];
  const float* alog = (const float*)d_in[5];
  const float* Dp = (const float*)d_in[6];
  const float* nw = (const float*)d_in[7];
  const float* w2 = (const float*)d_in[8];
  float* out = (float*)d_out;
  char* ws = (char*)d_ws;

  // Lifetime-aliased layout (stages S1 casts+GEMM1 / S2 conv+dt / S3 ssd / S4
  // gatenorm / S5 GEMM2). Peak live = 245.4 MB < ws.
  const size_t OFF_GATEB = 0;            // bf16 4096x4096   S1-S4
  const size_t OFF_XBC = 33554432;       // f32 4096x4352    S2-S3
  const size_t OFF_DTV = 104857600;      // f32 4096x64      S2-S3
  const size_t OFF_DAC = 105906176;      // f32 4096x64      S2-S3
  const size_t OFF_CB = 106954752;       // f32 16x256x256   S3
  const size_t OFF_Y = 111149056;        // f32 4096x4096    S3-S4
  const size_t OFF_ST = 178257920;       // f32 1024x64x128  S3
  const size_t OFF_PV = 211812352;       // f32 1024x64x128  S3
  const size_t OFF_PROJX = 111149056;    // f32 4096x4416    S1-S2 (aliases Y+ST head)
  const size_t OFF_HB = 183500800;       // bf16 4096x2048   S1 (aliases ST tail)
  const size_t OFF_W1B = 200278016;      // bf16 8704x2048   S1 (aliases ST tail+PV)
  const size_t OFF_W2B = 0;              // bf16 2048x4096   S5 (aliases GATEB)
  const size_t OFF_HGB = 33554432;       // bf16 4096x4096   S4-S5 (aliases XBC)
  const size_t NEED = 245366784;
  if (ws_size < NEED) {
    fprintf(stderr, "WS TOO SMALL: %zu < %zu\n", ws_size, NEED);
    return;
  }
  unsigned short* gateb = (unsigned short*)(ws + OFF_GATEB);
  float* xbc = (float*)(ws + OFF_XBC);
  float* dtv = (float*)(ws + OFF_DTV);
  float* dac = (float*)(ws + OFF_DAC);
  float* cbuf = (float*)(ws + OFF_CB);
  float* y = (float*)(ws + OFF_Y);
  float* st = (float*)(ws + OFF_ST);
  float* pv = (float*)(ws + OFF_PV);
  float* projx = (float*)(ws + OFF_PROJX);
  unsigned short* hb = (unsigned short*)(ws + OFF_HB);
  unsigned short* w1b = (unsigned short*)(ws + OFF_W1B);
  unsigned short* w2b = (unsigned short*)(ws + OFF_W2B);
  unsigned short* hgb = (unsigned short*)(ws + OFF_HGB);

  // S1
  k_cast_pad<<<4096, 256, 0, stream>>>(hidden, hb, (long)BL * DMODEL, (long)BL * DMODEL);
  k_cast_pad<<<8192, 256, 0, stream>>>(w1, w1b, (long)PROJD * DMODEL, (long)PROJ_PAD2 * DMODEL);
  k_gemm256<true><<<dim3(PROJ_PAD2 / 256, BL / 256), 512, 0, stream>>>(
      hb, w1b, nullptr, gateb, projx, PROJD, DMODEL);
  // S2
  k_conv_silu<<<dim3(17, BL), 256, 0, stream>>>(projx, cw, cb, xbc);
  k_dt<<<16, 256, 0, stream>>>(projx, dtb, alog, dtv, dac);
  // S3
  k_cb<<<dim3(4, 16), 256, 0, stream>>>(xbc, cbuf);
  k_diag<<<dim3(NH, NCH, BB), 256, 0, stream>>>(xbc, dtv, dac, cbuf, y, st);
  k_scan<<<dim3(NH, BB), 256, 0, stream>>>(st, dac, pv);
  k_off<<<dim3(NH, NCH, BB), 256, 0, stream>>>(xbc, dac, pv, Dp, y);
  // S4
  k_gatenorm<<<BL, 256, 0, stream>>>(y, gateb, nw, hgb);
  // S5
  k_cast_pad<<<8192, 256, 0, stream>>>(w2, w2b, (long)DMODEL * DIN, (long)DMODEL * DIN);
  k_gemm_bt<<<dim3(DMODEL / 128, BL / 128), 256, 0, stream>>>(
      hgb, w2b, out, DMODEL, DIN);
}